// Round 8
// baseline (676.361 us; speedup 1.0000x reference)
//
#include <hip/hip_runtime.h>

#define NN 100000
#define NE 1600000
#define EPSV 1e-5f
#define NTILE 1563          // ceil(NN/64)

typedef float f32x4 __attribute__((ext_vector_type(4)));
typedef short s16x8 __attribute__((ext_vector_type(8)));

__device__ __forceinline__ unsigned short f2bf(float f) {
  unsigned int u = __float_as_uint(f);
  u += 0x7fffu + ((u >> 16) & 1u);   // round-to-nearest-even
  return (unsigned short)(u >> 16);
}

__device__ __forceinline__ float bf2f(unsigned short s) {
  return __uint_as_float(((unsigned int)s) << 16);
}

__device__ __forceinline__ ushort4 pack4(float4 v) {
  ushort4 s;
  s.x = f2bf(v.x); s.y = f2bf(v.y); s.z = f2bf(v.z); s.w = f2bf(v.w);
  return s;
}

// ---------------- K1: histogram (4/5 of blocks) ∥ g1a partial GEMM (1/5) --------
// hist: cnt[src]++ per edge.  g1a: ph = [x, state[batch]] @ W1(x,state)^T (f32),
// stored in the per-thread register layout k_g2b reloads.
__global__ __launch_bounds__(256) void k_hist_g1a(
    const int* __restrict__ ei, int* __restrict__ cnt,
    const float4* __restrict__ x4, const float4* __restrict__ state4,
    const int* __restrict__ batch, const float4* __restrict__ w14,
    f32x4* __restrict__ ph) {
  __shared__ unsigned short lx[64][136];   // x(0..63) + state(64..127) per node
  __shared__ unsigned short lw[64][136];   // W1 x-cols + state-cols per out-row
  const int idx = blockIdx.x;
  const int tid = threadIdx.x;
  const bool is_g1a = ((idx % 5) == 2) && (idx / 5 < NTILE);
  if (!is_g1a) {
    int nga = idx / 5 + (((idx % 5) > 2) ? 1 : 0);   // g1a blocks before idx
    if (nga > NTILE) nga = NTILE;
    int e = (idx - nga) * 256 + tid;                 // hist_id * 256 + tid, exact NE
    atomicAdd(&cnt[ei[e]], 1);
    return;
  }
  const int tile = idx / 5;
  const int nodeBase = tile * 64;
#pragma unroll
  for (int i = 0; i < 4; ++i) {            // W1: x-part q0..15, state-part q32..47
    int t = tid + i * 256;
    int j = t >> 4, q = t & 15;
    *(ushort4*)&lw[j][q * 4]      = pack4(w14[j * 48 + q]);
    *(ushort4*)&lw[j][64 + q * 4] = pack4(w14[j * 48 + 32 + q]);
  }
#pragma unroll
  for (int i = 0; i < 4; ++i) {            // node tile: x + state[batch]
    int t = tid + i * 256;
    int node = t >> 4, q = t & 15;
    int g = nodeBase + node;
    float4 vx = {0,0,0,0}, vs = {0,0,0,0};
    if (g < NN) {
      vx = x4[(size_t)g * 16 + q];
      vs = state4[batch[g] * 16 + q];
    }
    *(ushort4*)&lx[node][q * 4]      = pack4(vx);
    *(ushort4*)&lx[node][64 + q * 4] = pack4(vs);
  }
  __syncthreads();
  const int lane = tid & 63, w = tid >> 6;
  const int rg = lane >> 4, ci = lane & 15;
  f32x4 acc[4] = {{0,0,0,0},{0,0,0,0},{0,0,0,0},{0,0,0,0}};
#pragma unroll
  for (int s = 0; s < 4; ++s) {            // 128 packed k-cols
    int k0 = 32 * s + rg * 8;
    s16x8 a = *(const s16x8*)&lx[w * 16 + ci][k0];
#pragma unroll
    for (int c = 0; c < 4; ++c) {
      s16x8 b = *(const s16x8*)&lw[c * 16 + ci][k0];
      acc[c] = __builtin_amdgcn_mfma_f32_16x16x32_bf16(a, b, acc[c], 0, 0, 0);
    }
  }
#pragma unroll
  for (int c = 0; c < 4; ++c)
    ph[(size_t)tile * 1024 + tid * 4 + c] = acc[c];
}

// ---------------- K2: exclusive scan of cnt -> csr, cur (one block) -------------
__global__ __launch_bounds__(1024) void k_scan(
    const int* __restrict__ cnt, int* __restrict__ csr, int* __restrict__ cur) {
  __shared__ int part[1024];
  const int t = threadIdx.x;
  const int base = t * 98;                 // 1024*98 = 100352 >= NN
  int s = 0;
  for (int i = 0; i < 98; ++i) {
    int n = base + i;
    if (n < NN) s += cnt[n];
  }
  part[t] = s;
  __syncthreads();
  for (int off = 1; off < 1024; off <<= 1) {   // Hillis-Steele inclusive scan
    int v = (t >= off) ? part[t - off] : 0;
    __syncthreads();
    part[t] += v;
    __syncthreads();
  }
  int run = (t == 0) ? 0 : part[t - 1];
  for (int i = 0; i < 98; ++i) {
    int n = base + i;
    if (n < NN) {
      csr[n] = run;
      cur[n] = run;
      run += cnt[n];
    }
  }
  if (t == 1023) csr[NN] = run;
}

// ---------------- K3: scatter-data: eab[cur[src]++] = bf16(ea[e]) ---------------
// Streaming coalesced read of ea (f32, 256B rows), random full-line 128B writes.
// Half-wave (32 lanes) per edge; each half-wave owns exactly 98 edges.
// NOTE: 98 % 4 == 2, so the last iteration must mask j+k >= 98 (r7 bug: edges
// 98,99 of each half-wave were double-scattered, corrupting neighbors' slots).
__global__ __launch_bounds__(256) void k_scat(
    const int* __restrict__ ei, int* __restrict__ cur,
    const float2* __restrict__ ea2, unsigned int* __restrict__ eab) {
  const int gid = blockIdx.x * 256 + threadIdx.x;   // 2048 blocks
  const int hw = gid >> 5;                 // 0..16383
  const int sub = gid & 31;
  const int lane = threadIdx.x & 63;
  const size_t e0 = (size_t)hw * 98;       // 16384*98 = 1,605,632 >= NE
  for (int j = 0; j < 98; j += 4) {
    size_t e = e0 + j;
    bool g0 =                 (e     < NE);
    bool g1 = (j + 1 < 98) && (e + 1 < NE);
    bool g2 = (j + 2 < 98) && (e + 2 < NE);
    bool g3 = (j + 3 < 98) && (e + 3 < NE);
    int p = 0;
    if (sub < 4) {
      size_t ee = e + sub;
      if ((j + sub < 98) && (ee < NE)) p = atomicAdd(&cur[ei[ee]], 1);
    }
    float2 d0 = {0,0}, d1 = {0,0}, d2 = {0,0}, d3 = {0,0};
    if (g0) d0 = ea2[(e + 0) * 32 + sub];
    if (g1) d1 = ea2[(e + 1) * 32 + sub];
    if (g2) d2 = ea2[(e + 2) * 32 + sub];
    if (g3) d3 = ea2[(e + 3) * 32 + sub];
    int p0 = __shfl(p, (lane & 32) + 0);
    int p1 = __shfl(p, (lane & 32) + 1);
    int p2 = __shfl(p, (lane & 32) + 2);
    int p3 = __shfl(p, (lane & 32) + 3);
    if (g0) eab[(size_t)p0 * 32 + sub] = ((unsigned int)f2bf(d0.y) << 16) | f2bf(d0.x);
    if (g1) eab[(size_t)p1 * 32 + sub] = ((unsigned int)f2bf(d1.y) << 16) | f2bf(d1.x);
    if (g2) eab[(size_t)p2 * 32 + sub] = ((unsigned int)f2bf(d2.y) << 16) | f2bf(d2.x);
    if (g3) eab[(size_t)p3 * 32 + sub] = ((unsigned int)f2bf(d3.y) << 16) | f2bf(d3.x);
  }
}

// ---------------- K4: fused gather-mean + g1b MFMA -> h1, stats S1/Q1 -----------
// Per 64-node tile: wave w gathers nodes w*16..w*16+15 (contiguous CSR spans,
// sequential 128B rows), means -> lv, then vmean @ W1v^T + ph -> h1.
__global__ __launch_bounds__(256) void k_g2b(
    const int* __restrict__ csr, const unsigned int* __restrict__ eab,
    const float4* __restrict__ w14, const float* __restrict__ b1,
    const f32x4* __restrict__ ph, unsigned short* __restrict__ h1,
    float* __restrict__ Sout, float* __restrict__ Qout) {
  __shared__ unsigned short lv[64][72];    // vmean tile
  __shared__ unsigned short lwv[64][72];   // W1 vm-cols; reused as out-tile
  __shared__ float ssum[64], ssq[64];
  const int tid = threadIdx.x;
  const int tile = blockIdx.x;
  const int nodeBase = tile * 64;
  if (tid < 64) { ssum[tid] = 0.f; ssq[tid] = 0.f; }
#pragma unroll
  for (int i = 0; i < 4; ++i) {            // W1 vm-cols (k=64..127)
    int t = tid + i * 256;
    int j = t >> 4, q = t & 15;
    *(ushort4*)&lwv[j][q * 4] = pack4(w14[j * 48 + 16 + q]);
  }
  const int lane = tid & 63, w = tid >> 6;
  const int half = lane >> 5, c = lane & 31;
  for (int k = 0; k < 16; ++k) {
    int n = nodeBase + w * 16 + k;
    float a0 = 0.f, a1 = 0.f;
    int deg = 0;
    if (n < NN) {
      int r0 = csr[n], r1 = csr[n + 1];
      deg = r1 - r0;
      const unsigned int* base = eab + (size_t)r0 * 32 + c;
      int r = half;
      for (; r + 6 < deg; r += 8) {        // 4 rows in flight per half-wave
        unsigned int u0 = base[(size_t)(r)     * 32];
        unsigned int u1 = base[(size_t)(r + 2) * 32];
        unsigned int u2 = base[(size_t)(r + 4) * 32];
        unsigned int u3 = base[(size_t)(r + 6) * 32];
        a0 += bf2f((unsigned short)(u0 & 0xffff)) + bf2f((unsigned short)(u1 & 0xffff))
            + bf2f((unsigned short)(u2 & 0xffff)) + bf2f((unsigned short)(u3 & 0xffff));
        a1 += bf2f((unsigned short)(u0 >> 16)) + bf2f((unsigned short)(u1 >> 16))
            + bf2f((unsigned short)(u2 >> 16)) + bf2f((unsigned short)(u3 >> 16));
      }
      for (; r < deg; r += 2) {
        unsigned int u = base[(size_t)r * 32];
        a0 += bf2f((unsigned short)(u & 0xffff));
        a1 += bf2f((unsigned short)(u >> 16));
      }
    }
    a0 += __shfl_xor(a0, 32);
    a1 += __shfl_xor(a1, 32);
    if (half == 0) {
      float inv = 1.0f / fmaxf((float)deg, 1.0f);
      unsigned int pk = ((unsigned int)f2bf(a1 * inv) << 16) | f2bf(a0 * inv);
      *(unsigned int*)&lv[w * 16 + k][c * 2] = pk;
    }
  }
  __syncthreads();
  const int rg = lane >> 4, ci = lane & 15;
  f32x4 acc[4];
#pragma unroll
  for (int cc = 0; cc < 4; ++cc) acc[cc] = ph[(size_t)tile * 1024 + tid * 4 + cc];
#pragma unroll
  for (int s = 0; s < 2; ++s) {
    int k0 = 32 * s + rg * 8;
    s16x8 a = *(const s16x8*)&lv[w * 16 + ci][k0];
#pragma unroll
    for (int cc = 0; cc < 4; ++cc) {
      s16x8 b = *(const s16x8*)&lwv[cc * 16 + ci][k0];
      acc[cc] = __builtin_amdgcn_mfma_f32_16x16x32_bf16(a, b, acc[cc], 0, 0, 0);
    }
  }
  __syncthreads();                         // lwv reads done; reuse as out-tile
  unsigned short (*lo)[72] = (unsigned short(*)[72])lwv;
#pragma unroll
  for (int cc = 0; cc < 4; ++cc) {
    int col = cc * 16 + ci;
    float bb = b1[col];
    float ls = 0.f, lq = 0.f;
#pragma unroll
    for (int r = 0; r < 4; ++r) {
      int row = w * 16 + rg * 4 + r;
      float v = fmaxf(acc[cc][r] + bb, 0.f);
      lo[row][col] = f2bf(v);
      if (nodeBase + row < NN) { ls += v; lq += v * v; }
    }
    atomicAdd(&ssum[col], ls);
    atomicAdd(&ssq[col], lq);
  }
  __syncthreads();
#pragma unroll
  for (int i = 0; i < 2; ++i) {            // coalesced 16B stores
    int t = tid + i * 256;
    int row = t >> 3, q = t & 7;
    int g = nodeBase + row;
    if (g < NN) *(s16x8*)&h1[(size_t)g * 64 + q * 8] = *(const s16x8*)&lo[row][q * 8];
  }
  if (tid < 64) {
    unsafeAtomicAdd(&Sout[tid], ssum[tid]);
    unsafeAtomicAdd(&Qout[tid], ssq[tid]);
  }
}

// ---------------- GEMM2/3 with in-kernel BN fold: out = [relu](A @ Wf^T + d) ----
template <bool RELU>
__global__ __launch_bounds__(256) void k_gemm64f(
    const s16x8* __restrict__ A8,     // bf16 [NN][64]
    const float* __restrict__ Wf,     // f32 [64][64] raw weights
    const float* __restrict__ bias,
    const float* __restrict__ gm, const float* __restrict__ bt,
    const float* __restrict__ Sin, const float* __restrict__ Qin,
    unsigned short* __restrict__ Obf,
    float* __restrict__ Sout, float* __restrict__ Qout) {
  __shared__ unsigned short la[64][72];    // A tile; reused as out-tile
  __shared__ unsigned short lwf[64][72];   // folded W bf16
  __shared__ float lA[64], lC[64], ld[64], red[256], ssum[64], ssq[64];
  const int tid = threadIdx.x;
  const int nodeBase = blockIdx.x * 64;
  if (tid < 64) {
    float mu = Sin[tid] * (1.0f / NN);
    float var = Qin[tid] * (1.0f / NN) - mu * mu;
    float a = gm[tid] * rsqrtf(var + EPSV);
    lA[tid] = a; lC[tid] = bt[tid] - mu * a;
    ssum[tid] = 0.f; ssq[tid] = 0.f;
  }
  __syncthreads();
#pragma unroll
  for (int i = 0; i < 2; ++i) {            // A tile: 512 x 16B
    int t = tid + i * 256;
    int row = t >> 3, q = t & 7;
    int g = nodeBase + row;
    s16x8 v = {};
    if (g < NN) v = A8[(size_t)g * 8 + q];
    *(s16x8*)&la[row][q * 8] = v;
  }
#pragma unroll
  for (int i = 0; i < 16; ++i) {           // fold weights by BN scale a_k
    int t = tid + i * 256;
    lwf[t >> 6][t & 63] = f2bf(Wf[t] * lA[t & 63]);
  }
  {                                        // folded bias partials
    int j = tid >> 2, p = tid & 3;
    const float* Wr = Wf + j * 64 + p * 16;
    float s = 0.f;
#pragma unroll
    for (int k = 0; k < 16; ++k) s += lC[p * 16 + k] * Wr[k];
    red[tid] = s;
  }
  __syncthreads();
  if (tid < 64) ld[tid] = bias[tid] + red[tid*4] + red[tid*4+1] + red[tid*4+2] + red[tid*4+3];
  __syncthreads();
  const int lane = tid & 63, w = tid >> 6;
  const int rg = lane >> 4, ci = lane & 15;
  f32x4 acc[4] = {{0,0,0,0},{0,0,0,0},{0,0,0,0},{0,0,0,0}};
#pragma unroll
  for (int s = 0; s < 2; ++s) {
    int k0 = 32 * s + rg * 8;
    s16x8 a = *(const s16x8*)&la[w * 16 + ci][k0];
#pragma unroll
    for (int c = 0; c < 4; ++c) {
      s16x8 b = *(const s16x8*)&lwf[c * 16 + ci][k0];
      acc[c] = __builtin_amdgcn_mfma_f32_16x16x32_bf16(a, b, acc[c], 0, 0, 0);
    }
  }
  __syncthreads();                         // reuse la as out-tile
  unsigned short (*lo)[72] = (unsigned short(*)[72])la;
#pragma unroll
  for (int c = 0; c < 4; ++c) {
    int col = c * 16 + ci;
    float dd = ld[col];
    float ls = 0.f, lq = 0.f;
#pragma unroll
    for (int r = 0; r < 4; ++r) {
      int row = w * 16 + rg * 4 + r;
      float v = acc[c][r] + dd;
      if (RELU) v = fmaxf(v, 0.f);
      lo[row][col] = f2bf(v);
      if (nodeBase + row < NN) { ls += v; lq += v * v; }
    }
    atomicAdd(&ssum[col], ls);
    atomicAdd(&ssq[col], lq);
  }
  __syncthreads();
#pragma unroll
  for (int i = 0; i < 2; ++i) {
    int t = tid + i * 256;
    int row = t >> 3, q = t & 7;
    int g = nodeBase + row;
    if (g < NN) *(s16x8*)&Obf[(size_t)g * 64 + q * 8] = *(const s16x8*)&lo[row][q * 8];
  }
  if (tid < 64) {
    unsafeAtomicAdd(&Sout[tid], ssum[tid]);
    unsafeAtomicAdd(&Qout[tid], ssq[tid]);
  }
}

// ---------------- final BN3 elementwise (bf16 in, f32 out) ----------------
__global__ __launch_bounds__(256) void k_bn3(
    const s16x8* __restrict__ h3b, const float* __restrict__ gm,
    const float* __restrict__ bt, const float* __restrict__ S,
    const float* __restrict__ Q, float4* __restrict__ out) {
  __shared__ float lA[64], lC[64];
  const int tid = threadIdx.x;
  if (tid < 64) {
    float mu = S[tid] * (1.0f / NN);
    float var = Q[tid] * (1.0f / NN) - mu * mu;
    float a = gm[tid] * rsqrtf(var + EPSV);
    lA[tid] = a;
    lC[tid] = bt[tid] - mu * a;
  }
  __syncthreads();
  const int total = NN * 8;                // short8 units
  for (int idx = blockIdx.x * 256 + tid; idx < total; idx += gridDim.x * 256) {
    s16x8 v = h3b[idx];
    int k = (idx & 7) * 8;
    float4 o0, o1;
    o0.x = bf2f((unsigned short)v[0]) * lA[k]     + lC[k];
    o0.y = bf2f((unsigned short)v[1]) * lA[k + 1] + lC[k + 1];
    o0.z = bf2f((unsigned short)v[2]) * lA[k + 2] + lC[k + 2];
    o0.w = bf2f((unsigned short)v[3]) * lA[k + 3] + lC[k + 3];
    o1.x = bf2f((unsigned short)v[4]) * lA[k + 4] + lC[k + 4];
    o1.y = bf2f((unsigned short)v[5]) * lA[k + 5] + lC[k + 5];
    o1.z = bf2f((unsigned short)v[6]) * lA[k + 6] + lC[k + 6];
    o1.w = bf2f((unsigned short)v[7]) * lA[k + 7] + lC[k + 7];
    out[idx * 2]     = o0;
    out[idx * 2 + 1] = o1;
  }
}

extern "C" void kernel_launch(void* const* d_in, const int* in_sizes, int n_in,
                              void* d_out, int out_size, void* d_ws, size_t ws_size,
                              hipStream_t stream) {
  const float* x     = (const float*)d_in[0];
  const int*   ei    = (const int*)d_in[1];
  const float* ea    = (const float*)d_in[2];
  const float* state = (const float*)d_in[3];
  const int*   batch = (const int*)d_in[4];
  const float* W1  = (const float*)d_in[5];
  const float* b1  = (const float*)d_in[6];
  const float* g1  = (const float*)d_in[7];
  const float* be1 = (const float*)d_in[8];
  const float* W2  = (const float*)d_in[9];
  const float* b2  = (const float*)d_in[10];
  const float* g2  = (const float*)d_in[11];
  const float* be2 = (const float*)d_in[12];
  const float* W3  = (const float*)d_in[13];
  const float* b3  = (const float*)d_in[14];
  const float* g3  = (const float*)d_in[15];
  const float* be3 = (const float*)d_in[16];

  // Workspace layout (ws_size ~1.6 GB per fill counters):
  //   [0,        400000)    cnt
  //   [400000,   401536)    stats S1 Q1 S2 Q2 S3 Q3
  //   [401536,   801792)    csr (100001 ints, padded)
  //   [801792,   1202048)   cur
  //   [1202048,  26810240)  ph f32 partial (1563*1024*16B)
  //   [26810240, 39610240)  h1 bf16
  //   [39610240, 52410240)  h2 bf16
  //   [52410240, 65210240)  h3 bf16
  //   [65210240, 270010240) eab bf16 permuted edge rows (1.6M x 128B)
  char* ws = (char*)d_ws;
  int*   cnt  = (int*)ws;
  float* S1   = (float*)(ws + 400000);
  float* Q1 = S1 + 64;
  float* S2 = S1 + 128;
  float* Q2 = S1 + 192;
  float* S3 = S1 + 256;
  float* Q3 = S1 + 320;
  int*            csr = (int*)(ws + 401536);
  int*            cur = (int*)(ws + 801792);
  f32x4*          ph  = (f32x4*)(ws + 1202048);
  unsigned short* h1  = (unsigned short*)(ws + 26810240);
  unsigned short* h2  = (unsigned short*)(ws + 39610240);
  unsigned short* h3b = (unsigned short*)(ws + 52410240);
  unsigned int*   eab = (unsigned int*)(ws + 65210240);

  hipMemsetAsync(ws, 0, 401536, stream);   // cnt + stats

  k_hist_g1a<<<6250 + NTILE, 256, 0, stream>>>(
      ei, cnt, (const float4*)x, (const float4*)state, batch,
      (const float4*)W1, ph);
  k_scan<<<1, 1024, 0, stream>>>(cnt, csr, cur);
  k_scat<<<2048, 256, 0, stream>>>(ei, cur, (const float2*)ea, eab);
  k_g2b<<<NTILE, 256, 0, stream>>>(csr, eab, (const float4*)W1, b1, ph,
                                   h1, S1, Q1);
  k_gemm64f<true><<<NTILE, 256, 0, stream>>>(
      (const s16x8*)h1, W2, b2, g1, be1, S1, Q1, h2, S2, Q2);
  k_gemm64f<false><<<NTILE, 256, 0, stream>>>(
      (const s16x8*)h2, W3, b3, g2, be2, S2, Q2, h3b, S3, Q3);
  k_bn3<<<2048, 256, 0, stream>>>((const s16x8*)h3b, g3, be3, S3, Q3, (float4*)d_out);
}

// Round 9
// 430.059 us; speedup vs baseline: 1.5727x; 1.5727x over previous
//
#include <hip/hip_runtime.h>

#define NN 100000
#define NE 1600000
#define EPSV 1e-5f
#define NTILE 1563          // ceil(NN/64)
#define SCB 196             // scan blocks: 196*512 = 100352 >= NN

typedef float f32x4 __attribute__((ext_vector_type(4)));
typedef short s16x8 __attribute__((ext_vector_type(8)));

__device__ __forceinline__ unsigned short f2bf(float f) {
  unsigned int u = __float_as_uint(f);
  u += 0x7fffu + ((u >> 16) & 1u);   // round-to-nearest-even
  return (unsigned short)(u >> 16);
}

__device__ __forceinline__ float bf2f(unsigned short s) {
  return __uint_as_float(((unsigned int)s) << 16);
}

__device__ __forceinline__ ushort4 pack4(float4 v) {
  ushort4 s;
  s.x = f2bf(v.x); s.y = f2bf(v.y); s.z = f2bf(v.z); s.w = f2bf(v.w);
  return s;
}

// ---------------- K1: histogram (4/5 of blocks) ∥ g1a partial GEMM (1/5) --------
__global__ __launch_bounds__(256) void k_hist_g1a(
    const int* __restrict__ ei, int* __restrict__ cnt,
    const float4* __restrict__ x4, const float4* __restrict__ state4,
    const int* __restrict__ batch, const float4* __restrict__ w14,
    f32x4* __restrict__ ph) {
  __shared__ unsigned short lx[64][136];   // x(0..63) + state(64..127) per node
  __shared__ unsigned short lw[64][136];   // W1 x-cols + state-cols per out-row
  const int idx = blockIdx.x;
  const int tid = threadIdx.x;
  const bool is_g1a = ((idx % 5) == 2) && (idx / 5 < NTILE);
  if (!is_g1a) {
    int nga = idx / 5 + (((idx % 5) > 2) ? 1 : 0);   // g1a blocks before idx
    if (nga > NTILE) nga = NTILE;
    int e = (idx - nga) * 256 + tid;                 // hist_id * 256 + tid, exact NE
    atomicAdd(&cnt[ei[e]], 1);
    return;
  }
  const int tile = idx / 5;
  const int nodeBase = tile * 64;
#pragma unroll
  for (int i = 0; i < 4; ++i) {            // W1: x-part q0..15, state-part q32..47
    int t = tid + i * 256;
    int j = t >> 4, q = t & 15;
    *(ushort4*)&lw[j][q * 4]      = pack4(w14[j * 48 + q]);
    *(ushort4*)&lw[j][64 + q * 4] = pack4(w14[j * 48 + 32 + q]);
  }
#pragma unroll
  for (int i = 0; i < 4; ++i) {            // node tile: x + state[batch]
    int t = tid + i * 256;
    int node = t >> 4, q = t & 15;
    int g = nodeBase + node;
    float4 vx = {0,0,0,0}, vs = {0,0,0,0};
    if (g < NN) {
      vx = x4[(size_t)g * 16 + q];
      vs = state4[batch[g] * 16 + q];
    }
    *(ushort4*)&lx[node][q * 4]      = pack4(vx);
    *(ushort4*)&lx[node][64 + q * 4] = pack4(vs);
  }
  __syncthreads();
  const int lane = tid & 63, w = tid >> 6;
  const int rg = lane >> 4, ci = lane & 15;
  f32x4 acc[4] = {{0,0,0,0},{0,0,0,0},{0,0,0,0},{0,0,0,0}};
#pragma unroll
  for (int s = 0; s < 4; ++s) {            // 128 packed k-cols
    int k0 = 32 * s + rg * 8;
    s16x8 a = *(const s16x8*)&lx[w * 16 + ci][k0];
#pragma unroll
    for (int c = 0; c < 4; ++c) {
      s16x8 b = *(const s16x8*)&lw[c * 16 + ci][k0];
      acc[c] = __builtin_amdgcn_mfma_f32_16x16x32_bf16(a, b, acc[c], 0, 0, 0);
    }
  }
#pragma unroll
  for (int c = 0; c < 4; ++c)
    ph[(size_t)tile * 1024 + tid * 4 + c] = acc[c];
}

// ---------------- K2a: per-block reduction of 512 counts -> bsum[b] -------------
__global__ __launch_bounds__(256) void k_scanA(
    const int* __restrict__ cnt, int* __restrict__ bsum) {
  __shared__ int red[256];
  const int t = threadIdx.x;
  const int i = blockIdx.x * 512 + t * 2;
  int s = 0;
  if (i < NN)     s += cnt[i];
  if (i + 1 < NN) s += cnt[i + 1];
  red[t] = s;
  __syncthreads();
  for (int off = 128; off > 0; off >>= 1) {
    if (t < off) red[t] += red[t + off];
    __syncthreads();
  }
  if (t == 0) bsum[blockIdx.x] = red[0];
}

// ---------------- K2b: exclusive scan of 196 block sums (one block) -------------
__global__ __launch_bounds__(256) void k_scanB(
    const int* __restrict__ bsum, int* __restrict__ boff, int* __restrict__ csr) {
  __shared__ int sc[256];
  const int t = threadIdx.x;
  int v = (t < SCB) ? bsum[t] : 0;
  sc[t] = v;
  __syncthreads();
  for (int off = 1; off < 256; off <<= 1) {
    int u = (t >= off) ? sc[t - off] : 0;
    __syncthreads();
    sc[t] += u;
    __syncthreads();
  }
  if (t < SCB) boff[t] = sc[t] - v;        // exclusive
  if (t == 0) csr[NN] = NE;                // total is structurally constant
}

// ---------------- K2c: block-local scan + offset -> csr, cur --------------------
__global__ __launch_bounds__(256) void k_scanC(
    const int* __restrict__ cnt, const int* __restrict__ boff,
    int* __restrict__ csr, int* __restrict__ cur) {
  __shared__ int sc[256];
  const int t = threadIdx.x;
  const int i = blockIdx.x * 512 + t * 2;
  int e0 = (i < NN) ? cnt[i] : 0;
  int e1 = (i + 1 < NN) ? cnt[i + 1] : 0;
  int pair = e0 + e1;
  sc[t] = pair;
  __syncthreads();
  for (int off = 1; off < 256; off <<= 1) {
    int u = (t >= off) ? sc[t - off] : 0;
    __syncthreads();
    sc[t] += u;
    __syncthreads();
  }
  int base = boff[blockIdx.x] + sc[t] - pair;   // exclusive prefix for i
  if (i < NN)     { csr[i] = base;          cur[i] = base; }
  if (i + 1 < NN) { csr[i + 1] = base + e0; cur[i + 1] = base + e0; }
}

// ---------------- K3: scatter-data: eab[cur[src]++] = bf16(ea[e]) ---------------
// Streaming coalesced read of ea (f32, 256B rows), random full-line 128B writes.
// Half-wave (32 lanes) per edge; each half-wave owns exactly 98 edges.
// 98 % 4 == 2 -> last iteration masks j+k >= 98 (r7 bug fix).
__global__ __launch_bounds__(256) void k_scat(
    const int* __restrict__ ei, int* __restrict__ cur,
    const float2* __restrict__ ea2, unsigned int* __restrict__ eab) {
  const int gid = blockIdx.x * 256 + threadIdx.x;   // 2048 blocks
  const int hw = gid >> 5;                 // 0..16383
  const int sub = gid & 31;
  const int lane = threadIdx.x & 63;
  const size_t e0 = (size_t)hw * 98;       // 16384*98 = 1,605,632 >= NE
  for (int j = 0; j < 98; j += 4) {
    size_t e = e0 + j;
    bool g0 =                 (e     < NE);
    bool g1 = (j + 1 < 98) && (e + 1 < NE);
    bool g2 = (j + 2 < 98) && (e + 2 < NE);
    bool g3 = (j + 3 < 98) && (e + 3 < NE);
    int p = 0;
    if (sub < 4) {
      size_t ee = e + sub;
      if ((j + sub < 98) && (ee < NE)) p = atomicAdd(&cur[ei[ee]], 1);
    }
    float2 d0 = {0,0}, d1 = {0,0}, d2 = {0,0}, d3 = {0,0};
    if (g0) d0 = ea2[(e + 0) * 32 + sub];
    if (g1) d1 = ea2[(e + 1) * 32 + sub];
    if (g2) d2 = ea2[(e + 2) * 32 + sub];
    if (g3) d3 = ea2[(e + 3) * 32 + sub];
    int p0 = __shfl(p, (lane & 32) + 0);
    int p1 = __shfl(p, (lane & 32) + 1);
    int p2 = __shfl(p, (lane & 32) + 2);
    int p3 = __shfl(p, (lane & 32) + 3);
    if (g0) eab[(size_t)p0 * 32 + sub] = ((unsigned int)f2bf(d0.y) << 16) | f2bf(d0.x);
    if (g1) eab[(size_t)p1 * 32 + sub] = ((unsigned int)f2bf(d1.y) << 16) | f2bf(d1.x);
    if (g2) eab[(size_t)p2 * 32 + sub] = ((unsigned int)f2bf(d2.y) << 16) | f2bf(d2.x);
    if (g3) eab[(size_t)p3 * 32 + sub] = ((unsigned int)f2bf(d3.y) << 16) | f2bf(d3.x);
  }
}

// ---------------- K4: fused gather-mean + g1b MFMA -> h1, stats S1/Q1 -----------
__global__ __launch_bounds__(256) void k_g2b(
    const int* __restrict__ csr, const unsigned int* __restrict__ eab,
    const float4* __restrict__ w14, const float* __restrict__ b1,
    const f32x4* __restrict__ ph, unsigned short* __restrict__ h1,
    float* __restrict__ Sout, float* __restrict__ Qout) {
  __shared__ unsigned short lv[64][72];    // vmean tile
  __shared__ unsigned short lwv[64][72];   // W1 vm-cols; reused as out-tile
  __shared__ float ssum[64], ssq[64];
  const int tid = threadIdx.x;
  const int tile = blockIdx.x;
  const int nodeBase = tile * 64;
  if (tid < 64) { ssum[tid] = 0.f; ssq[tid] = 0.f; }
#pragma unroll
  for (int i = 0; i < 4; ++i) {            // W1 vm-cols (k=64..127)
    int t = tid + i * 256;
    int j = t >> 4, q = t & 15;
    *(ushort4*)&lwv[j][q * 4] = pack4(w14[j * 48 + 16 + q]);
  }
  const int lane = tid & 63, w = tid >> 6;
  const int half = lane >> 5, c = lane & 31;
  for (int k = 0; k < 16; ++k) {
    int n = nodeBase + w * 16 + k;
    float a0 = 0.f, a1 = 0.f;
    int deg = 0;
    if (n < NN) {
      int r0 = csr[n], r1 = csr[n + 1];
      deg = r1 - r0;
      const unsigned int* base = eab + (size_t)r0 * 32 + c;
      int r = half;
      for (; r + 6 < deg; r += 8) {        // 4 rows in flight per half-wave
        unsigned int u0 = base[(size_t)(r)     * 32];
        unsigned int u1 = base[(size_t)(r + 2) * 32];
        unsigned int u2 = base[(size_t)(r + 4) * 32];
        unsigned int u3 = base[(size_t)(r + 6) * 32];
        a0 += bf2f((unsigned short)(u0 & 0xffff)) + bf2f((unsigned short)(u1 & 0xffff))
            + bf2f((unsigned short)(u2 & 0xffff)) + bf2f((unsigned short)(u3 & 0xffff));
        a1 += bf2f((unsigned short)(u0 >> 16)) + bf2f((unsigned short)(u1 >> 16))
            + bf2f((unsigned short)(u2 >> 16)) + bf2f((unsigned short)(u3 >> 16));
      }
      for (; r < deg; r += 2) {
        unsigned int u = base[(size_t)r * 32];
        a0 += bf2f((unsigned short)(u & 0xffff));
        a1 += bf2f((unsigned short)(u >> 16));
      }
    }
    a0 += __shfl_xor(a0, 32);
    a1 += __shfl_xor(a1, 32);
    if (half == 0) {
      float inv = 1.0f / fmaxf((float)deg, 1.0f);
      unsigned int pk = ((unsigned int)f2bf(a1 * inv) << 16) | f2bf(a0 * inv);
      *(unsigned int*)&lv[w * 16 + k][c * 2] = pk;
    }
  }
  __syncthreads();
  const int rg = lane >> 4, ci = lane & 15;
  f32x4 acc[4];
#pragma unroll
  for (int cc = 0; cc < 4; ++cc) acc[cc] = ph[(size_t)tile * 1024 + tid * 4 + cc];
#pragma unroll
  for (int s = 0; s < 2; ++s) {
    int k0 = 32 * s + rg * 8;
    s16x8 a = *(const s16x8*)&lv[w * 16 + ci][k0];
#pragma unroll
    for (int cc = 0; cc < 4; ++cc) {
      s16x8 b = *(const s16x8*)&lwv[cc * 16 + ci][k0];
      acc[cc] = __builtin_amdgcn_mfma_f32_16x16x32_bf16(a, b, acc[cc], 0, 0, 0);
    }
  }
  __syncthreads();                         // lwv reads done; reuse as out-tile
  unsigned short (*lo)[72] = (unsigned short(*)[72])lwv;
#pragma unroll
  for (int cc = 0; cc < 4; ++cc) {
    int col = cc * 16 + ci;
    float bb = b1[col];
    float ls = 0.f, lq = 0.f;
#pragma unroll
    for (int r = 0; r < 4; ++r) {
      int row = w * 16 + rg * 4 + r;
      float v = fmaxf(acc[cc][r] + bb, 0.f);
      lo[row][col] = f2bf(v);
      if (nodeBase + row < NN) { ls += v; lq += v * v; }
    }
    atomicAdd(&ssum[col], ls);
    atomicAdd(&ssq[col], lq);
  }
  __syncthreads();
#pragma unroll
  for (int i = 0; i < 2; ++i) {            // coalesced 16B stores
    int t = tid + i * 256;
    int row = t >> 3, q = t & 7;
    int g = nodeBase + row;
    if (g < NN) *(s16x8*)&h1[(size_t)g * 64 + q * 8] = *(const s16x8*)&lo[row][q * 8];
  }
  if (tid < 64) {
    unsafeAtomicAdd(&Sout[tid], ssum[tid]);
    unsafeAtomicAdd(&Qout[tid], ssq[tid]);
  }
}

// ---------------- GEMM2/3 with in-kernel BN fold: out = [relu](A @ Wf^T + d) ----
template <bool RELU>
__global__ __launch_bounds__(256) void k_gemm64f(
    const s16x8* __restrict__ A8,     // bf16 [NN][64]
    const float* __restrict__ Wf,     // f32 [64][64] raw weights
    const float* __restrict__ bias,
    const float* __restrict__ gm, const float* __restrict__ bt,
    const float* __restrict__ Sin, const float* __restrict__ Qin,
    unsigned short* __restrict__ Obf,
    float* __restrict__ Sout, float* __restrict__ Qout) {
  __shared__ unsigned short la[64][72];    // A tile; reused as out-tile
  __shared__ unsigned short lwf[64][72];   // folded W bf16
  __shared__ float lA[64], lC[64], ld[64], red[256], ssum[64], ssq[64];
  const int tid = threadIdx.x;
  const int nodeBase = blockIdx.x * 64;
  if (tid < 64) {
    float mu = Sin[tid] * (1.0f / NN);
    float var = Qin[tid] * (1.0f / NN) - mu * mu;
    float a = gm[tid] * rsqrtf(var + EPSV);
    lA[tid] = a; lC[tid] = bt[tid] - mu * a;
    ssum[tid] = 0.f; ssq[tid] = 0.f;
  }
  __syncthreads();
#pragma unroll
  for (int i = 0; i < 2; ++i) {            // A tile: 512 x 16B
    int t = tid + i * 256;
    int row = t >> 3, q = t & 7;
    int g = nodeBase + row;
    s16x8 v = {};
    if (g < NN) v = A8[(size_t)g * 8 + q];
    *(s16x8*)&la[row][q * 8] = v;
  }
#pragma unroll
  for (int i = 0; i < 16; ++i) {           // fold weights by BN scale a_k
    int t = tid + i * 256;
    lwf[t >> 6][t & 63] = f2bf(Wf[t] * lA[t & 63]);
  }
  {                                        // folded bias partials
    int j = tid >> 2, p = tid & 3;
    const float* Wr = Wf + j * 64 + p * 16;
    float s = 0.f;
#pragma unroll
    for (int k = 0; k < 16; ++k) s += lC[p * 16 + k] * Wr[k];
    red[tid] = s;
  }
  __syncthreads();
  if (tid < 64) ld[tid] = bias[tid] + red[tid*4] + red[tid*4+1] + red[tid*4+2] + red[tid*4+3];
  __syncthreads();
  const int lane = tid & 63, w = tid >> 6;
  const int rg = lane >> 4, ci = lane & 15;
  f32x4 acc[4] = {{0,0,0,0},{0,0,0,0},{0,0,0,0},{0,0,0,0}};
#pragma unroll
  for (int s = 0; s < 2; ++s) {
    int k0 = 32 * s + rg * 8;
    s16x8 a = *(const s16x8*)&la[w * 16 + ci][k0];
#pragma unroll
    for (int c = 0; c < 4; ++c) {
      s16x8 b = *(const s16x8*)&lwf[c * 16 + ci][k0];
      acc[c] = __builtin_amdgcn_mfma_f32_16x16x32_bf16(a, b, acc[c], 0, 0, 0);
    }
  }
  __syncthreads();                         // reuse la as out-tile
  unsigned short (*lo)[72] = (unsigned short(*)[72])la;
#pragma unroll
  for (int c = 0; c < 4; ++c) {
    int col = c * 16 + ci;
    float dd = ld[col];
    float ls = 0.f, lq = 0.f;
#pragma unroll
    for (int r = 0; r < 4; ++r) {
      int row = w * 16 + rg * 4 + r;
      float v = acc[c][r] + dd;
      if (RELU) v = fmaxf(v, 0.f);
      lo[row][col] = f2bf(v);
      if (nodeBase + row < NN) { ls += v; lq += v * v; }
    }
    atomicAdd(&ssum[col], ls);
    atomicAdd(&ssq[col], lq);
  }
  __syncthreads();
#pragma unroll
  for (int i = 0; i < 2; ++i) {
    int t = tid + i * 256;
    int row = t >> 3, q = t & 7;
    int g = nodeBase + row;
    if (g < NN) *(s16x8*)&Obf[(size_t)g * 64 + q * 8] = *(const s16x8*)&lo[row][q * 8];
  }
  if (tid < 64) {
    unsafeAtomicAdd(&Sout[tid], ssum[tid]);
    unsafeAtomicAdd(&Qout[tid], ssq[tid]);
  }
}

// ---------------- final BN3 elementwise (bf16 in, f32 out) ----------------
__global__ __launch_bounds__(256) void k_bn3(
    const s16x8* __restrict__ h3b, const float* __restrict__ gm,
    const float* __restrict__ bt, const float* __restrict__ S,
    const float* __restrict__ Q, float4* __restrict__ out) {
  __shared__ float lA[64], lC[64];
  const int tid = threadIdx.x;
  if (tid < 64) {
    float mu = S[tid] * (1.0f / NN);
    float var = Q[tid] * (1.0f / NN) - mu * mu;
    float a = gm[tid] * rsqrtf(var + EPSV);
    lA[tid] = a;
    lC[tid] = bt[tid] - mu * a;
  }
  __syncthreads();
  const int total = NN * 8;                // short8 units
  for (int idx = blockIdx.x * 256 + tid; idx < total; idx += gridDim.x * 256) {
    s16x8 v = h3b[idx];
    int k = (idx & 7) * 8;
    float4 o0, o1;
    o0.x = bf2f((unsigned short)v[0]) * lA[k]     + lC[k];
    o0.y = bf2f((unsigned short)v[1]) * lA[k + 1] + lC[k + 1];
    o0.z = bf2f((unsigned short)v[2]) * lA[k + 2] + lC[k + 2];
    o0.w = bf2f((unsigned short)v[3]) * lA[k + 3] + lC[k + 3];
    o1.x = bf2f((unsigned short)v[4]) * lA[k + 4] + lC[k + 4];
    o1.y = bf2f((unsigned short)v[5]) * lA[k + 5] + lC[k + 5];
    o1.z = bf2f((unsigned short)v[6]) * lA[k + 6] + lC[k + 6];
    o1.w = bf2f((unsigned short)v[7]) * lA[k + 7] + lC[k + 7];
    out[idx * 2]     = o0;
    out[idx * 2 + 1] = o1;
  }
}

extern "C" void kernel_launch(void* const* d_in, const int* in_sizes, int n_in,
                              void* d_out, int out_size, void* d_ws, size_t ws_size,
                              hipStream_t stream) {
  const float* x     = (const float*)d_in[0];
  const int*   ei    = (const int*)d_in[1];
  const float* ea    = (const float*)d_in[2];
  const float* state = (const float*)d_in[3];
  const int*   batch = (const int*)d_in[4];
  const float* W1  = (const float*)d_in[5];
  const float* b1  = (const float*)d_in[6];
  const float* g1  = (const float*)d_in[7];
  const float* be1 = (const float*)d_in[8];
  const float* W2  = (const float*)d_in[9];
  const float* b2  = (const float*)d_in[10];
  const float* g2  = (const float*)d_in[11];
  const float* be2 = (const float*)d_in[12];
  const float* W3  = (const float*)d_in[13];
  const float* b3  = (const float*)d_in[14];
  const float* g3  = (const float*)d_in[15];
  const float* be3 = (const float*)d_in[16];

  // Workspace layout:
  //   [0,        400000)    cnt
  //   [400000,   401536)    stats S1 Q1 S2 Q2 S3 Q3
  //   [401536,   801792)    csr (100001 ints, padded)
  //   [801792,   1202048)   cur
  //   [1202048,  1203072)   bsum/boff (196 ints each, padded)
  //   [1204224,  26812416)  ph f32 partial (1563*1024*16B)
  //   [26812416, 39612416)  h1 bf16
  //   [39612416, 52412416)  h2 bf16
  //   [52412416, 65212416)  h3 bf16
  //   [65212416, 270012416) eab bf16 permuted edge rows (1.6M x 128B)
  char* ws = (char*)d_ws;
  int*   cnt  = (int*)ws;
  float* S1   = (float*)(ws + 400000);
  float* Q1 = S1 + 64;
  float* S2 = S1 + 128;
  float* Q2 = S1 + 192;
  float* S3 = S1 + 256;
  float* Q3 = S1 + 320;
  int*            csr  = (int*)(ws + 401536);
  int*            cur  = (int*)(ws + 801792);
  int*            bsum = (int*)(ws + 1202048);
  int*            boff = bsum + 256;
  f32x4*          ph   = (f32x4*)(ws + 1204224);
  unsigned short* h1   = (unsigned short*)(ws + 26812416);
  unsigned short* h2   = (unsigned short*)(ws + 39612416);
  unsigned short* h3b  = (unsigned short*)(ws + 52412416);
  unsigned int*   eab  = (unsigned int*)(ws + 65212416);

  hipMemsetAsync(ws, 0, 401536, stream);   // cnt + stats

  k_hist_g1a<<<6250 + NTILE, 256, 0, stream>>>(
      ei, cnt, (const float4*)x, (const float4*)state, batch,
      (const float4*)W1, ph);
  k_scanA<<<SCB, 256, 0, stream>>>(cnt, bsum);
  k_scanB<<<1, 256, 0, stream>>>(bsum, boff, csr);
  k_scanC<<<SCB, 256, 0, stream>>>(cnt, boff, csr, cur);
  k_scat<<<2048, 256, 0, stream>>>(ei, cur, (const float2*)ea, eab);
  k_g2b<<<NTILE, 256, 0, stream>>>(csr, eab, (const float4*)W1, b1, ph,
                                   h1, S1, Q1);
  k_gemm64f<true><<<NTILE, 256, 0, stream>>>(
      (const s16x8*)h1, W2, b2, g1, be1, S1, Q1, h2, S2, Q2);
  k_gemm64f<false><<<NTILE, 256, 0, stream>>>(
      (const s16x8*)h2, W3, b3, g2, be2, S2, Q2, h3b, S3, Q3);
  k_bn3<<<2048, 256, 0, stream>>>((const s16x8*)h3b, g3, be3, S3, Q3, (float4*)d_out);
}

// Round 10
// 409.633 us; speedup vs baseline: 1.6511x; 1.0499x over previous
//
#include <hip/hip_runtime.h>

#define NN 100000
#define NE 1600000
#define EPSV 1e-5f
#define NTILE 1563          // ceil(NN/64)
#define CVB 2048            // convert blocks
#define BKB 6250            // bucket blocks (6250*256 = NE)

typedef float f32x4 __attribute__((ext_vector_type(4)));
typedef short s16x8 __attribute__((ext_vector_type(8)));

__device__ __forceinline__ unsigned short f2bf(float f) {
  unsigned int u = __float_as_uint(f);
  u += 0x7fffu + ((u >> 16) & 1u);   // round-to-nearest-even
  return (unsigned short)(u >> 16);
}

__device__ __forceinline__ float bf2f(unsigned short s) {
  return __uint_as_float(((unsigned int)s) << 16);
}

__device__ __forceinline__ ushort4 pack4(float4 v) {
  ushort4 s;
  s.x = f2bf(v.x); s.y = f2bf(v.y); s.z = f2bf(v.z); s.w = f2bf(v.w);
  return s;
}

// ---- K1: three block families: convert (ea f32->bf16) ∥ bucket ∥ g1a ----------
// convert: eab bf16 copy of ea (204.8 MB, fits L3); nt loads to reduce pollution.
// bucket:  eids[src][pos] = e (padded 64) + cnt histogram.
// g1a:     ph = [x, state[batch]] @ W1(x,state)^T (f32), layout-matched to K2.
__global__ __launch_bounds__(256) void k_pre(
    const int* __restrict__ ei, int* __restrict__ cnt, int* __restrict__ eids,
    const f32x4* __restrict__ ea4, ushort4* __restrict__ eab4,
    const float4* __restrict__ x4, const float4* __restrict__ state4,
    const int* __restrict__ batch, const float4* __restrict__ w14,
    f32x4* __restrict__ ph) {
  const int idx = blockIdx.x;
  const int tid = threadIdx.x;
  const bool is_g1a = ((idx % 5) == 2) && (idx / 5 < NTILE);
  if (!is_g1a) {
    int nga = idx / 5 + (((idx % 5) > 2) ? 1 : 0);   // g1a blocks before idx
    if (nga > NTILE) nga = NTILE;
    int nid = idx - nga;                             // 0..CVB+BKB-1
    if (nid < CVB) {
      // ---- convert family: grid-stride over NE*16 float4 ----
      const int TOT = NE * 16;
      for (int i = nid * 256 + tid; i < TOT; i += CVB * 256) {
        f32x4 v = __builtin_nontemporal_load(ea4 + i);
        ushort4 p;
        p.x = f2bf(v[0]); p.y = f2bf(v[1]); p.z = f2bf(v[2]); p.w = f2bf(v[3]);
        eab4[i] = p;
      }
    } else {
      // ---- bucket family ----
      int e = (nid - CVB) * 256 + tid;               // exact NE
      int src = ei[e];
      int pos = atomicAdd(&cnt[src], 1);
      if (pos < 64) eids[(size_t)src * 64 + pos] = e;
    }
    return;
  }
  // ---- g1a family ----
  __shared__ unsigned short lx[64][136];   // x(0..63) + state(64..127) per node
  __shared__ unsigned short lw[64][136];   // W1 x-cols + state-cols per out-row
  const int tile = idx / 5;
  const int nodeBase = tile * 64;
#pragma unroll
  for (int i = 0; i < 4; ++i) {            // W1: x-part q0..15, state-part q32..47
    int t = tid + i * 256;
    int j = t >> 4, q = t & 15;
    *(ushort4*)&lw[j][q * 4]      = pack4(w14[j * 48 + q]);
    *(ushort4*)&lw[j][64 + q * 4] = pack4(w14[j * 48 + 32 + q]);
  }
#pragma unroll
  for (int i = 0; i < 4; ++i) {            // node tile: x + state[batch]
    int t = tid + i * 256;
    int node = t >> 4, q = t & 15;
    int g = nodeBase + node;
    float4 vx = {0,0,0,0}, vs = {0,0,0,0};
    if (g < NN) {
      vx = x4[(size_t)g * 16 + q];
      vs = state4[batch[g] * 16 + q];
    }
    *(ushort4*)&lx[node][q * 4]      = pack4(vx);
    *(ushort4*)&lx[node][64 + q * 4] = pack4(vs);
  }
  __syncthreads();
  const int lane = tid & 63, w = tid >> 6;
  const int rg = lane >> 4, ci = lane & 15;
  f32x4 acc[4] = {{0,0,0,0},{0,0,0,0},{0,0,0,0},{0,0,0,0}};
#pragma unroll
  for (int s = 0; s < 4; ++s) {            // 128 packed k-cols
    int k0 = 32 * s + rg * 8;
    s16x8 a = *(const s16x8*)&lx[w * 16 + ci][k0];
#pragma unroll
    for (int c = 0; c < 4; ++c) {
      s16x8 b = *(const s16x8*)&lw[c * 16 + ci][k0];
      acc[c] = __builtin_amdgcn_mfma_f32_16x16x32_bf16(a, b, acc[c], 0, 0, 0);
    }
  }
#pragma unroll
  for (int c = 0; c < 4; ++c)
    ph[(size_t)tile * 1024 + tid * 4 + c] = acc[c];
}

// ---- K2: fused gather-mean (random bf16 rows, L3-resident) + g1b MFMA ---------
// Per 64-node tile: wave w owns nodes w*16..+15. Row = 32 dwords (128B);
// half-wave per row, 2 rows/step x 4 streams = 8 rows in flight.
__global__ __launch_bounds__(256) void k_gather_g1b(
    const int* __restrict__ cnt, const int* __restrict__ eids,
    const unsigned int* __restrict__ eab,
    const float4* __restrict__ w14, const float* __restrict__ b1,
    const f32x4* __restrict__ ph, unsigned short* __restrict__ h1,
    float* __restrict__ Sout, float* __restrict__ Qout) {
  __shared__ unsigned short lv[64][72];    // vmean tile
  __shared__ unsigned short lwv[64][72];   // W1 vm-cols; reused as out-tile
  __shared__ float ssum[64], ssq[64];
  const int tid = threadIdx.x;
  const int tile = blockIdx.x;
  const int nodeBase = tile * 64;
  if (tid < 64) { ssum[tid] = 0.f; ssq[tid] = 0.f; }
#pragma unroll
  for (int i = 0; i < 4; ++i) {            // W1 vm-cols (k=64..127)
    int t = tid + i * 256;
    int j = t >> 4, q = t & 15;
    *(ushort4*)&lwv[j][q * 4] = pack4(w14[j * 48 + 16 + q]);
  }
  const int lane = tid & 63, w = tid >> 6;
  const int grp = lane >> 5, c = lane & 31;
  for (int k = 0; k < 16; ++k) {
    int n = nodeBase + w * 16 + k;
    float a0 = 0.f, a1 = 0.f;
    int cfull = 0;
    if (n < NN) {
      const int* elist = eids + (size_t)n * 64;
      cfull = cnt[n];
      int deg = cfull < 64 ? cfull : 64;
      int rm = deg - 1;
      for (int r0 = 0; r0 < deg; r0 += 8) {
        int ra = r0 + grp,     rb = r0 + 2 + grp;
        int rc = r0 + 4 + grp, rd = r0 + 6 + grp;
        int ia = elist[ra < deg ? ra : rm];
        int ib = elist[rb < deg ? rb : rm];
        int ic = elist[rc < deg ? rc : rm];
        int id = elist[rd < deg ? rd : rm];
        unsigned int ua = eab[(size_t)ia * 32 + c];
        unsigned int ub = eab[(size_t)ib * 32 + c];
        unsigned int uc = eab[(size_t)ic * 32 + c];
        unsigned int ud = eab[(size_t)id * 32 + c];
        float ma = ra < deg ? 1.f : 0.f, mb = rb < deg ? 1.f : 0.f;
        float mc = rc < deg ? 1.f : 0.f, md = rd < deg ? 1.f : 0.f;
        a0 += ma * bf2f((unsigned short)(ua & 0xffff))
            + mb * bf2f((unsigned short)(ub & 0xffff))
            + mc * bf2f((unsigned short)(uc & 0xffff))
            + md * bf2f((unsigned short)(ud & 0xffff));
        a1 += ma * bf2f((unsigned short)(ua >> 16))
            + mb * bf2f((unsigned short)(ub >> 16))
            + mc * bf2f((unsigned short)(uc >> 16))
            + md * bf2f((unsigned short)(ud >> 16));
      }
    }
    a0 += __shfl_xor(a0, 32);
    a1 += __shfl_xor(a1, 32);
    if (grp == 0) {
      float inv = 1.0f / fmaxf((float)cfull, 1.0f);
      unsigned int pk = ((unsigned int)f2bf(a1 * inv) << 16) | f2bf(a0 * inv);
      *(unsigned int*)&lv[w * 16 + k][c * 2] = pk;
    }
  }
  __syncthreads();
  const int rg = lane >> 4, ci = lane & 15;
  f32x4 acc[4];
#pragma unroll
  for (int cc = 0; cc < 4; ++cc) acc[cc] = ph[(size_t)tile * 1024 + tid * 4 + cc];
#pragma unroll
  for (int s = 0; s < 2; ++s) {
    int k0 = 32 * s + rg * 8;
    s16x8 a = *(const s16x8*)&lv[w * 16 + ci][k0];
#pragma unroll
    for (int cc = 0; cc < 4; ++cc) {
      s16x8 b = *(const s16x8*)&lwv[cc * 16 + ci][k0];
      acc[cc] = __builtin_amdgcn_mfma_f32_16x16x32_bf16(a, b, acc[cc], 0, 0, 0);
    }
  }
  __syncthreads();                         // lwv reads done; reuse as out-tile
  unsigned short (*lo)[72] = (unsigned short(*)[72])lwv;
#pragma unroll
  for (int cc = 0; cc < 4; ++cc) {
    int col = cc * 16 + ci;
    float bb = b1[col];
    float ls = 0.f, lq = 0.f;
#pragma unroll
    for (int r = 0; r < 4; ++r) {
      int row = w * 16 + rg * 4 + r;
      float v = fmaxf(acc[cc][r] + bb, 0.f);
      lo[row][col] = f2bf(v);
      if (nodeBase + row < NN) { ls += v; lq += v * v; }
    }
    atomicAdd(&ssum[col], ls);
    atomicAdd(&ssq[col], lq);
  }
  __syncthreads();
#pragma unroll
  for (int i = 0; i < 2; ++i) {            // coalesced 16B stores
    int t = tid + i * 256;
    int row = t >> 3, q = t & 7;
    int g = nodeBase + row;
    if (g < NN) *(s16x8*)&h1[(size_t)g * 64 + q * 8] = *(const s16x8*)&lo[row][q * 8];
  }
  if (tid < 64) {
    unsafeAtomicAdd(&Sout[tid], ssum[tid]);
    unsafeAtomicAdd(&Qout[tid], ssq[tid]);
  }
}

// ---- GEMM2/3 with in-kernel BN fold: out = [relu](A @ Wf^T + d) ---------------
template <bool RELU>
__global__ __launch_bounds__(256) void k_gemm64f(
    const s16x8* __restrict__ A8,     // bf16 [NN][64]
    const float* __restrict__ Wf,     // f32 [64][64] raw weights
    const float* __restrict__ bias,
    const float* __restrict__ gm, const float* __restrict__ bt,
    const float* __restrict__ Sin, const float* __restrict__ Qin,
    unsigned short* __restrict__ Obf,
    float* __restrict__ Sout, float* __restrict__ Qout) {
  __shared__ unsigned short la[64][72];    // A tile; reused as out-tile
  __shared__ unsigned short lwf[64][72];   // folded W bf16
  __shared__ float lA[64], lC[64], ld[64], red[256], ssum[64], ssq[64];
  const int tid = threadIdx.x;
  const int nodeBase = blockIdx.x * 64;
  if (tid < 64) {
    float mu = Sin[tid] * (1.0f / NN);
    float var = Qin[tid] * (1.0f / NN) - mu * mu;
    float a = gm[tid] * rsqrtf(var + EPSV);
    lA[tid] = a; lC[tid] = bt[tid] - mu * a;
    ssum[tid] = 0.f; ssq[tid] = 0.f;
  }
  __syncthreads();
#pragma unroll
  for (int i = 0; i < 2; ++i) {            // A tile: 512 x 16B
    int t = tid + i * 256;
    int row = t >> 3, q = t & 7;
    int g = nodeBase + row;
    s16x8 v = {};
    if (g < NN) v = A8[(size_t)g * 8 + q];
    *(s16x8*)&la[row][q * 8] = v;
  }
#pragma unroll
  for (int i = 0; i < 16; ++i) {           // fold weights by BN scale a_k
    int t = tid + i * 256;
    lwf[t >> 6][t & 63] = f2bf(Wf[t] * lA[t & 63]);
  }
  {                                        // folded bias partials
    int j = tid >> 2, p = tid & 3;
    const float* Wr = Wf + j * 64 + p * 16;
    float s = 0.f;
#pragma unroll
    for (int k = 0; k < 16; ++k) s += lC[p * 16 + k] * Wr[k];
    red[tid] = s;
  }
  __syncthreads();
  if (tid < 64) ld[tid] = bias[tid] + red[tid*4] + red[tid*4+1] + red[tid*4+2] + red[tid*4+3];
  __syncthreads();
  const int lane = tid & 63, w = tid >> 6;
  const int rg = lane >> 4, ci = lane & 15;
  f32x4 acc[4] = {{0,0,0,0},{0,0,0,0},{0,0,0,0},{0,0,0,0}};
#pragma unroll
  for (int s = 0; s < 2; ++s) {
    int k0 = 32 * s + rg * 8;
    s16x8 a = *(const s16x8*)&la[w * 16 + ci][k0];
#pragma unroll
    for (int c = 0; c < 4; ++c) {
      s16x8 b = *(const s16x8*)&lwf[c * 16 + ci][k0];
      acc[c] = __builtin_amdgcn_mfma_f32_16x16x32_bf16(a, b, acc[c], 0, 0, 0);
    }
  }
  __syncthreads();                         // reuse la as out-tile
  unsigned short (*lo)[72] = (unsigned short(*)[72])la;
#pragma unroll
  for (int c = 0; c < 4; ++c) {
    int col = c * 16 + ci;
    float dd = ld[col];
    float ls = 0.f, lq = 0.f;
#pragma unroll
    for (int r = 0; r < 4; ++r) {
      int row = w * 16 + rg * 4 + r;
      float v = acc[c][r] + dd;
      if (RELU) v = fmaxf(v, 0.f);
      lo[row][col] = f2bf(v);
      if (nodeBase + row < NN) { ls += v; lq += v * v; }
    }
    atomicAdd(&ssum[col], ls);
    atomicAdd(&ssq[col], lq);
  }
  __syncthreads();
#pragma unroll
  for (int i = 0; i < 2; ++i) {
    int t = tid + i * 256;
    int row = t >> 3, q = t & 7;
    int g = nodeBase + row;
    if (g < NN) *(s16x8*)&Obf[(size_t)g * 64 + q * 8] = *(const s16x8*)&lo[row][q * 8];
  }
  if (tid < 64) {
    unsafeAtomicAdd(&Sout[tid], ssum[tid]);
    unsafeAtomicAdd(&Qout[tid], ssq[tid]);
  }
}

// ---- final BN3 elementwise (bf16 in, f32 out) ---------------------------------
__global__ __launch_bounds__(256) void k_bn3(
    const s16x8* __restrict__ h3b, const float* __restrict__ gm,
    const float* __restrict__ bt, const float* __restrict__ S,
    const float* __restrict__ Q, float4* __restrict__ out) {
  __shared__ float lA[64], lC[64];
  const int tid = threadIdx.x;
  if (tid < 64) {
    float mu = S[tid] * (1.0f / NN);
    float var = Q[tid] * (1.0f / NN) - mu * mu;
    float a = gm[tid] * rsqrtf(var + EPSV);
    lA[tid] = a;
    lC[tid] = bt[tid] - mu * a;
  }
  __syncthreads();
  const int total = NN * 8;                // short8 units
  for (int idx = blockIdx.x * 256 + tid; idx < total; idx += gridDim.x * 256) {
    s16x8 v = h3b[idx];
    int k = (idx & 7) * 8;
    float4 o0, o1;
    o0.x = bf2f((unsigned short)v[0]) * lA[k]     + lC[k];
    o0.y = bf2f((unsigned short)v[1]) * lA[k + 1] + lC[k + 1];
    o0.z = bf2f((unsigned short)v[2]) * lA[k + 2] + lC[k + 2];
    o0.w = bf2f((unsigned short)v[3]) * lA[k + 3] + lC[k + 3];
    o1.x = bf2f((unsigned short)v[4]) * lA[k + 4] + lC[k + 4];
    o1.y = bf2f((unsigned short)v[5]) * lA[k + 5] + lC[k + 5];
    o1.z = bf2f((unsigned short)v[6]) * lA[k + 6] + lC[k + 6];
    o1.w = bf2f((unsigned short)v[7]) * lA[k + 7] + lC[k + 7];
    out[idx * 2]     = o0;
    out[idx * 2 + 1] = o1;
  }
}

extern "C" void kernel_launch(void* const* d_in, const int* in_sizes, int n_in,
                              void* d_out, int out_size, void* d_ws, size_t ws_size,
                              hipStream_t stream) {
  const float* x     = (const float*)d_in[0];
  const int*   ei    = (const int*)d_in[1];
  const float* ea    = (const float*)d_in[2];
  const float* state = (const float*)d_in[3];
  const int*   batch = (const int*)d_in[4];
  const float* W1  = (const float*)d_in[5];
  const float* b1  = (const float*)d_in[6];
  const float* g1  = (const float*)d_in[7];
  const float* be1 = (const float*)d_in[8];
  const float* W2  = (const float*)d_in[9];
  const float* b2  = (const float*)d_in[10];
  const float* g2  = (const float*)d_in[11];
  const float* be2 = (const float*)d_in[12];
  const float* W3  = (const float*)d_in[13];
  const float* b3  = (const float*)d_in[14];
  const float* g3  = (const float*)d_in[15];
  const float* be3 = (const float*)d_in[16];

  // Workspace layout:
  //   [0,        400000)    cnt
  //   [400000,   401536)    stats S1 Q1 S2 Q2 S3 Q3
  //   [401536,   26018432)  eids (int, padded 64/node)
  //   [26018432, 51626624)  ph f32 partial (1563*1024*16B)
  //   [51626624, 64426624)  h1 bf16
  //   [64426624, 77226624)  h2 bf16
  //   [77226624, 90026624)  h3 bf16
  //   [90026624, 294826624) eab bf16 edge rows (1.6M x 128B = 204.8 MB, L3-sized)
  char* ws = (char*)d_ws;
  int*   cnt  = (int*)ws;
  float* S1   = (float*)(ws + 400000);
  float* Q1 = S1 + 64;
  float* S2 = S1 + 128;
  float* Q2 = S1 + 192;
  float* S3 = S1 + 256;
  float* Q3 = S1 + 320;
  int*            eids = (int*)(ws + 401536);
  f32x4*          ph   = (f32x4*)(ws + 26018432);
  unsigned short* h1   = (unsigned short*)(ws + 51626624);
  unsigned short* h2   = (unsigned short*)(ws + 64426624);
  unsigned short* h3b  = (unsigned short*)(ws + 77226624);
  unsigned int*   eab  = (unsigned int*)(ws + 90026624);

  hipMemsetAsync(ws, 0, 401536, stream);   // cnt + stats

  k_pre<<<CVB + BKB + NTILE, 256, 0, stream>>>(
      ei, cnt, eids, (const f32x4*)ea, (ushort4*)eab,
      (const float4*)x, (const float4*)state, batch, (const float4*)W1, ph);
  k_gather_g1b<<<NTILE, 256, 0, stream>>>(cnt, eids, eab, (const float4*)W1,
                                          b1, ph, h1, S1, Q1);
  k_gemm64f<true><<<NTILE, 256, 0, stream>>>(
      (const s16x8*)h1, W2, b2, g1, be1, S1, Q1, h2, S2, Q2);
  k_gemm64f<false><<<NTILE, 256, 0, stream>>>(
      (const s16x8*)h2, W3, b3, g2, be2, S2, Q2, h3b, S3, Q3);
  k_bn3<<<2048, 256, 0, stream>>>((const s16x8*)h3b, g3, be3, S3, Q3, (float4*)d_out);
}

// Round 12
// 374.327 us; speedup vs baseline: 1.8069x; 1.0943x over previous
//
#include <hip/hip_runtime.h>

#define NN 100000
#define NE 1600000
#define EPSV 1e-5f
#define NTILE 1563          // ceil(NN/64)

typedef float f32x4 __attribute__((ext_vector_type(4)));
typedef short s16x8 __attribute__((ext_vector_type(8)));

__device__ __forceinline__ unsigned short f2bf(float f) {
  unsigned int u = __float_as_uint(f);
  u += 0x7fffu + ((u >> 16) & 1u);   // round-to-nearest-even
  return (unsigned short)(u >> 16);
}

__device__ __forceinline__ float bf2f(unsigned short s) {
  return __uint_as_float(((unsigned int)s) << 16);
}

__device__ __forceinline__ ushort4 pack4(float4 v) {
  ushort4 s;
  s.x = f2bf(v.x); s.y = f2bf(v.y); s.z = f2bf(v.z); s.w = f2bf(v.w);
  return s;
}

__device__ __forceinline__ ushort4 pack4v(f32x4 v) {
  ushort4 s;
  s.x = f2bf(v[0]); s.y = f2bf(v[1]); s.z = f2bf(v[2]); s.w = f2bf(v[3]);
  return s;
}

// ---- K1: bucket (4/5 of blocks) ∥ g1a partial GEMM (1/5) ----------------------
__global__ __launch_bounds__(256) void k_bucket_g1a(
    const int* __restrict__ ei, int* __restrict__ cnt, int* __restrict__ eids,
    const float4* __restrict__ x4, const float4* __restrict__ state4,
    const int* __restrict__ batch, const float4* __restrict__ w14,
    f32x4* __restrict__ ph) {
  __shared__ unsigned short lx[64][136];   // x(0..63) + state(64..127) per node
  __shared__ unsigned short lw[64][136];   // W1 x-cols + state-cols per out-row
  const int idx = blockIdx.x;
  const int tid = threadIdx.x;
  const bool is_g1a = ((idx % 5) == 2) && (idx / 5 < NTILE);
  if (!is_g1a) {
    int nga = idx / 5 + (((idx % 5) > 2) ? 1 : 0);   // g1a blocks before idx
    if (nga > NTILE) nga = NTILE;
    int e = (idx - nga) * 256 + tid;                 // bucket_id * 256 + tid
    int src = ei[e];
    int pos = atomicAdd(&cnt[src], 1);
    if (pos < 64) eids[(size_t)src * 64 + pos] = e;
    return;
  }
  const int tile = idx / 5;
  const int nodeBase = tile * 64;
#pragma unroll
  for (int i = 0; i < 4; ++i) {            // W1: x-part q0..15, state-part q32..47
    int t = tid + i * 256;
    int j = t >> 4, q = t & 15;
    *(ushort4*)&lw[j][q * 4]      = pack4(w14[j * 48 + q]);
    *(ushort4*)&lw[j][64 + q * 4] = pack4(w14[j * 48 + 32 + q]);
  }
#pragma unroll
  for (int i = 0; i < 4; ++i) {            // node tile: x + state[batch]
    int t = tid + i * 256;
    int node = t >> 4, q = t & 15;
    int g = nodeBase + node;
    float4 vx = {0,0,0,0}, vs = {0,0,0,0};
    if (g < NN) {
      vx = x4[(size_t)g * 16 + q];
      vs = state4[batch[g] * 16 + q];
    }
    *(ushort4*)&lx[node][q * 4]      = pack4(vx);
    *(ushort4*)&lx[node][64 + q * 4] = pack4(vs);
  }
  __syncthreads();
  const int lane = tid & 63, w = tid >> 6;
  const int rg = lane >> 4, ci = lane & 15;
  f32x4 acc[4] = {{0,0,0,0},{0,0,0,0},{0,0,0,0},{0,0,0,0}};
#pragma unroll
  for (int s = 0; s < 4; ++s) {            // 128 packed k-cols
    int k0 = 32 * s + rg * 8;
    s16x8 a = *(const s16x8*)&lx[w * 16 + ci][k0];
#pragma unroll
    for (int c = 0; c < 4; ++c) {
      s16x8 b = *(const s16x8*)&lw[c * 16 + ci][k0];
      acc[c] = __builtin_amdgcn_mfma_f32_16x16x32_bf16(a, b, acc[c], 0, 0, 0);
    }
  }
#pragma unroll
  for (int c = 0; c < 4; ++c)
    ph[(size_t)tile * 1024 + tid * 4 + c] = acc[c];
}

// ---- gather: vmb[n] = bf16 mean of edge_attr rows of node n -------------------
// Persistent: 2048 blocks x 4 waves; each wave owns 13 consecutive nodes.
// 32 row-slots (8 streams x 4 lane-groups); loads are exec-masked so clamped
// slots (deg<32) issue NO transaction; nt hint on the zero-reuse ea stream.
__global__ __launch_bounds__(256) void k_gather(
    const int* __restrict__ cnt, const int* __restrict__ eids,
    const f32x4* __restrict__ ea4, ushort4* __restrict__ vmb4) {
  int wid = (blockIdx.x * 256 + threadIdx.x) >> 6;   // 0..8191
  int lane = threadIdx.x & 63;
  int grp = lane >> 4, q = lane & 15;
  int n0 = wid * 13;
  int nend = n0 + 13 < NN ? n0 + 13 : NN;
  for (int n = n0; n < nend; ++n) {
    const int* elist = eids + (size_t)n * 64;
    int c = cnt[n];
    int m = c < 64 ? c : 64;
    float ax = 0.f, ay = 0.f, az = 0.f, aw = 0.f;
    {
      int r0 = grp,      r1 = 4 + grp,  r2 = 8 + grp,  r3 = 12 + grp;
      int r4 = 16 + grp, r5 = 20 + grp, r6 = 24 + grp, r7 = 28 + grp;
      f32x4 v0 = {0,0,0,0}, v1 = {0,0,0,0}, v2 = {0,0,0,0}, v3 = {0,0,0,0};
      f32x4 v4 = {0,0,0,0}, v5 = {0,0,0,0}, v6 = {0,0,0,0}, v7 = {0,0,0,0};
      if (r0 < m) v0 = __builtin_nontemporal_load(ea4 + (size_t)elist[r0] * 16 + q);
      if (r1 < m) v1 = __builtin_nontemporal_load(ea4 + (size_t)elist[r1] * 16 + q);
      if (r2 < m) v2 = __builtin_nontemporal_load(ea4 + (size_t)elist[r2] * 16 + q);
      if (r3 < m) v3 = __builtin_nontemporal_load(ea4 + (size_t)elist[r3] * 16 + q);
      if (r4 < m) v4 = __builtin_nontemporal_load(ea4 + (size_t)elist[r4] * 16 + q);
      if (r5 < m) v5 = __builtin_nontemporal_load(ea4 + (size_t)elist[r5] * 16 + q);
      if (r6 < m) v6 = __builtin_nontemporal_load(ea4 + (size_t)elist[r6] * 16 + q);
      if (r7 < m) v7 = __builtin_nontemporal_load(ea4 + (size_t)elist[r7] * 16 + q);
      ax += v0[0] + v1[0] + v2[0] + v3[0] + v4[0] + v5[0] + v6[0] + v7[0];
      ay += v0[1] + v1[1] + v2[1] + v3[1] + v4[1] + v5[1] + v6[1] + v7[1];
      az += v0[2] + v1[2] + v2[2] + v3[2] + v4[2] + v5[2] + v6[2] + v7[2];
      aw += v0[3] + v1[3] + v2[3] + v3[3] + v4[3] + v5[3] + v6[3] + v7[3];
    }
    if (m > 32) {                          // rare tail (P ~ 2e-4)
      for (int e = 32; e < m; e += 16) {
        int r0 = e + grp, r1 = e + 4 + grp, r2 = e + 8 + grp, r3 = e + 12 + grp;
        f32x4 v0 = {0,0,0,0}, v1 = {0,0,0,0}, v2 = {0,0,0,0}, v3 = {0,0,0,0};
        if (r0 < m) v0 = __builtin_nontemporal_load(ea4 + (size_t)elist[r0] * 16 + q);
        if (r1 < m) v1 = __builtin_nontemporal_load(ea4 + (size_t)elist[r1] * 16 + q);
        if (r2 < m) v2 = __builtin_nontemporal_load(ea4 + (size_t)elist[r2] * 16 + q);
        if (r3 < m) v3 = __builtin_nontemporal_load(ea4 + (size_t)elist[r3] * 16 + q);
        ax += v0[0] + v1[0] + v2[0] + v3[0];
        ay += v0[1] + v1[1] + v2[1] + v3[1];
        az += v0[2] + v1[2] + v2[2] + v3[2];
        aw += v0[3] + v1[3] + v2[3] + v3[3];
      }
    }
    ax += __shfl_xor(ax, 16); ay += __shfl_xor(ay, 16);
    az += __shfl_xor(az, 16); aw += __shfl_xor(aw, 16);
    ax += __shfl_xor(ax, 32); ay += __shfl_xor(ay, 32);
    az += __shfl_xor(az, 32); aw += __shfl_xor(aw, 32);
    if (lane < 16) {
      float inv = 1.0f / fmaxf((float)c, 1.0f);
      f32x4 r; r[0] = ax * inv; r[1] = ay * inv; r[2] = az * inv; r[3] = aw * inv;
      vmb4[(size_t)n * 16 + lane] = pack4v(r);
    }
  }
}

// ---- g1b: h1 = relu(ph + vmean @ W1v^T + b1), stats S1/Q1 ---------------------
__global__ __launch_bounds__(256) void k_g1b(
    const ushort4* __restrict__ vmb4, const float4* __restrict__ w14,
    const float* __restrict__ b1, const f32x4* __restrict__ ph,
    unsigned short* __restrict__ h1,
    float* __restrict__ Sout, float* __restrict__ Qout) {
  __shared__ unsigned short lv[64][72];    // vmean tile
  __shared__ unsigned short lwv[64][72];   // W1 vm-cols; reused as out-tile
  __shared__ float ssum[64], ssq[64];
  const int tid = threadIdx.x;
  const int tile = blockIdx.x;
  const int nodeBase = tile * 64;
  if (tid < 64) { ssum[tid] = 0.f; ssq[tid] = 0.f; }
#pragma unroll
  for (int i = 0; i < 4; ++i) {
    int t = tid + i * 256;
    int j = t >> 4, q = t & 15;
    *(ushort4*)&lwv[j][q * 4] = pack4(w14[j * 48 + 16 + q]);   // cols 64..127
    int g = nodeBase + j;
    ushort4 vm = {0,0,0,0};
    if (g < NN) vm = vmb4[(size_t)g * 16 + q];
    *(ushort4*)&lv[j][q * 4] = vm;
  }
  __syncthreads();
  const int lane = tid & 63, w = tid >> 6;
  const int rg = lane >> 4, ci = lane & 15;
  f32x4 acc[4];
#pragma unroll
  for (int c = 0; c < 4; ++c) acc[c] = ph[(size_t)tile * 1024 + tid * 4 + c];
#pragma unroll
  for (int s = 0; s < 2; ++s) {
    int k0 = 32 * s + rg * 8;
    s16x8 a = *(const s16x8*)&lv[w * 16 + ci][k0];
#pragma unroll
    for (int c = 0; c < 4; ++c) {
      s16x8 b = *(const s16x8*)&lwv[c * 16 + ci][k0];
      acc[c] = __builtin_amdgcn_mfma_f32_16x16x32_bf16(a, b, acc[c], 0, 0, 0);
    }
  }
  __syncthreads();                         // lwv reads done; reuse as out-tile
  unsigned short (*lo)[72] = (unsigned short(*)[72])lwv;
#pragma unroll
  for (int c = 0; c < 4; ++c) {
    int col = c * 16 + ci;
    float bb = b1[col];
    float ls = 0.f, lq = 0.f;
#pragma unroll
    for (int r = 0; r < 4; ++r) {
      int row = w * 16 + rg * 4 + r;
      float v = fmaxf(acc[c][r] + bb, 0.f);
      lo[row][col] = f2bf(v);
      if (nodeBase + row < NN) { ls += v; lq += v * v; }
    }
    atomicAdd(&ssum[col], ls);
    atomicAdd(&ssq[col], lq);
  }
  __syncthreads();
#pragma unroll
  for (int i = 0; i < 2; ++i) {            // coalesced 16B stores
    int t = tid + i * 256;
    int row = t >> 3, q = t & 7;
    int g = nodeBase + row;
    if (g < NN) *(s16x8*)&h1[(size_t)g * 64 + q * 8] = *(const s16x8*)&lo[row][q * 8];
  }
  if (tid < 64) {
    unsafeAtomicAdd(&Sout[tid], ssum[tid]);
    unsafeAtomicAdd(&Qout[tid], ssq[tid]);
  }
}

// ---- GEMM2/3 with in-kernel BN fold: out = [relu](A @ Wf^T + d) ---------------
template <bool RELU>
__global__ __launch_bounds__(256) void k_gemm64f(
    const s16x8* __restrict__ A8,     // bf16 [NN][64]
    const float* __restrict__ Wf,     // f32 [64][64] raw weights
    const float* __restrict__ bias,
    const float* __restrict__ gm, const float* __restrict__ bt,
    const float* __restrict__ Sin, const float* __restrict__ Qin,
    unsigned short* __restrict__ Obf,
    float* __restrict__ Sout, float* __restrict__ Qout) {
  __shared__ unsigned short la[64][72];    // A tile; reused as out-tile
  __shared__ unsigned short lwf[64][72];   // folded W bf16
  __shared__ float lA[64], lC[64], ld[64], red[256], ssum[64], ssq[64];
  const int tid = threadIdx.x;
  const int nodeBase = blockIdx.x * 64;
  if (tid < 64) {
    float mu = Sin[tid] * (1.0f / NN);
    float var = Qin[tid] * (1.0f / NN) - mu * mu;
    float a = gm[tid] * rsqrtf(var + EPSV);
    lA[tid] = a; lC[tid] = bt[tid] - mu * a;
    ssum[tid] = 0.f; ssq[tid] = 0.f;
  }
  __syncthreads();
#pragma unroll
  for (int i = 0; i < 2; ++i) {            // A tile: 512 x 16B
    int t = tid + i * 256;
    int row = t >> 3, q = t & 7;
    int g = nodeBase + row;
    s16x8 v = {};
    if (g < NN) v = A8[(size_t)g * 8 + q];
    *(s16x8*)&la[row][q * 8] = v;
  }
#pragma unroll
  for (int i = 0; i < 16; ++i) {           // fold weights by BN scale a_k
    int t = tid + i * 256;
    lwf[t >> 6][t & 63] = f2bf(Wf[t] * lA[t & 63]);
  }
  {                                        // folded bias partials
    int j = tid >> 2, p = tid & 3;
    const float* Wr = Wf + j * 64 + p * 16;
    float s = 0.f;
#pragma unroll
    for (int k = 0; k < 16; ++k) s += lC[p * 16 + k] * Wr[k];
    red[tid] = s;
  }
  __syncthreads();
  if (tid < 64) ld[tid] = bias[tid] + red[tid*4] + red[tid*4+1] + red[tid*4+2] + red[tid*4+3];
  __syncthreads();
  const int lane = tid & 63, w = tid >> 6;
  const int rg = lane >> 4, ci = lane & 15;
  f32x4 acc[4] = {{0,0,0,0},{0,0,0,0},{0,0,0,0},{0,0,0,0}};
#pragma unroll
  for (int s = 0; s < 2; ++s) {
    int k0 = 32 * s + rg * 8;
    s16x8 a = *(const s16x8*)&la[w * 16 + ci][k0];
#pragma unroll
    for (int c = 0; c < 4; ++c) {
      s16x8 b = *(const s16x8*)&lwf[c * 16 + ci][k0];
      acc[c] = __builtin_amdgcn_mfma_f32_16x16x32_bf16(a, b, acc[c], 0, 0, 0);
    }
  }
  __syncthreads();                         // reuse la as out-tile
  unsigned short (*lo)[72] = (unsigned short(*)[72])la;
#pragma unroll
  for (int c = 0; c < 4; ++c) {
    int col = c * 16 + ci;
    float dd = ld[col];
    float ls = 0.f, lq = 0.f;
#pragma unroll
    for (int r = 0; r < 4; ++r) {
      int row = w * 16 + rg * 4 + r;
      float v = acc[c][r] + dd;
      if (RELU) v = fmaxf(v, 0.f);
      lo[row][col] = f2bf(v);
      if (nodeBase + row < NN) { ls += v; lq += v * v; }
    }
    atomicAdd(&ssum[col], ls);
    atomicAdd(&ssq[col], lq);
  }
  __syncthreads();
#pragma unroll
  for (int i = 0; i < 2; ++i) {
    int t = tid + i * 256;
    int row = t >> 3, q = t & 7;
    int g = nodeBase + row;
    if (g < NN) *(s16x8*)&Obf[(size_t)g * 64 + q * 8] = *(const s16x8*)&lo[row][q * 8];
  }
  if (tid < 64) {
    unsafeAtomicAdd(&Sout[tid], ssum[tid]);
    unsafeAtomicAdd(&Qout[tid], ssq[tid]);
  }
}

// ---- final BN3 elementwise (bf16 in, f32 out) ---------------------------------
__global__ __launch_bounds__(256) void k_bn3(
    const s16x8* __restrict__ h3b, const float* __restrict__ gm,
    const float* __restrict__ bt, const float* __restrict__ S,
    const float* __restrict__ Q, float4* __restrict__ out) {
  __shared__ float lA[64], lC[64];
  const int tid = threadIdx.x;
  if (tid < 64) {
    float mu = S[tid] * (1.0f / NN);
    float var = Q[tid] * (1.0f / NN) - mu * mu;
    float a = gm[tid] * rsqrtf(var + EPSV);
    lA[tid] = a;
    lC[tid] = bt[tid] - mu * a;
  }
  __syncthreads();
  const int total = NN * 8;                // short8 units
  for (int idx = blockIdx.x * 256 + tid; idx < total; idx += gridDim.x * 256) {
    s16x8 v = h3b[idx];
    int k = (idx & 7) * 8;
    float4 o0, o1;
    o0.x = bf2f((unsigned short)v[0]) * lA[k]     + lC[k];
    o0.y = bf2f((unsigned short)v[1]) * lA[k + 1] + lC[k + 1];
    o0.z = bf2f((unsigned short)v[2]) * lA[k + 2] + lC[k + 2];
    o0.w = bf2f((unsigned short)v[3]) * lA[k + 3] + lC[k + 3];
    o1.x = bf2f((unsigned short)v[4]) * lA[k + 4] + lC[k + 4];
    o1.y = bf2f((unsigned short)v[5]) * lA[k + 5] + lC[k + 5];
    o1.z = bf2f((unsigned short)v[6]) * lA[k + 6] + lC[k + 6];
    o1.w = bf2f((unsigned short)v[7]) * lA[k + 7] + lC[k + 7];
    out[idx * 2]     = o0;
    out[idx * 2 + 1] = o1;
  }
}

extern "C" void kernel_launch(void* const* d_in, const int* in_sizes, int n_in,
                              void* d_out, int out_size, void* d_ws, size_t ws_size,
                              hipStream_t stream) {
  const float* x     = (const float*)d_in[0];
  const int*   ei    = (const int*)d_in[1];
  const float* ea    = (const float*)d_in[2];
  const float* state = (const float*)d_in[3];
  const int*   batch = (const int*)d_in[4];
  const float* W1  = (const float*)d_in[5];
  const float* b1  = (const float*)d_in[6];
  const float* g1  = (const float*)d_in[7];
  const float* be1 = (const float*)d_in[8];
  const float* W2  = (const float*)d_in[9];
  const float* b2  = (const float*)d_in[10];
  const float* g2  = (const float*)d_in[11];
  const float* be2 = (const float*)d_in[12];
  const float* W3  = (const float*)d_in[13];
  const float* b3  = (const float*)d_in[14];
  const float* g3  = (const float*)d_in[15];
  const float* be3 = (const float*)d_in[16];

  // Workspace layout:
  //   [0,        400000)   cnt
  //   [400000,   401536)   stats S1 Q1 S2 Q2 S3 Q3
  //   [401536,  26018432)  eids (int, 64/node)   == h3 bf16 alias (12.8 MB)
  //   [26018432,38818432)  vmb bf16 mean         == h2 bf16 alias
  //   [38818432,51618432)  h1 bf16
  //   [51618432,77218432)  ph f32 partial (g1a -> g1b)
  char* ws = (char*)d_ws;
  int*   cnt  = (int*)ws;
  float* S1   = (float*)(ws + 400000);
  float* Q1 = S1 + 64;
  float* S2 = S1 + 128;
  float* Q2 = S1 + 192;
  float* S3 = S1 + 256;
  float* Q3 = S1 + 320;
  int*            eids = (int*)(ws + 401536);
  unsigned short* h3b  = (unsigned short*)(ws + 401536);   // alias eids
  unsigned short* vmb  = (unsigned short*)(ws + 26018432);
  unsigned short* h2   = (unsigned short*)(ws + 26018432); // alias vmb
  unsigned short* h1   = (unsigned short*)(ws + 38818432);
  f32x4*          ph   = (f32x4*)(ws + 51618432);

  hipMemsetAsync(ws, 0, 401536, stream);   // cnt + stats

  k_bucket_g1a<<<6250 + NTILE, 256, 0, stream>>>(
      ei, cnt, eids, (const float4*)x, (const float4*)state, batch,
      (const float4*)W1, ph);
  k_gather<<<2048, 256, 0, stream>>>(cnt, eids, (const f32x4*)ea, (ushort4*)vmb);
  k_g1b<<<NTILE, 256, 0, stream>>>((const ushort4*)vmb, (const float4*)W1,
                                   b1, ph, h1, S1, Q1);
  k_gemm64f<true><<<NTILE, 256, 0, stream>>>(
      (const s16x8*)h1, W2, b2, g1, be1, S1, Q1, h2, S2, Q2);
  k_gemm64f<false><<<NTILE, 256, 0, stream>>>(
      (const s16x8*)h2, W3, b3, g2, be2, S2, Q2, h3b, S3, Q3);
  k_bn3<<<2048, 256, 0, stream>>>((const s16x8*)h3b, g3, be3, S3, Q3, (float4*)d_out);
}

// Round 13
// 343.105 us; speedup vs baseline: 1.9713x; 1.0910x over previous
//
#include <hip/hip_runtime.h>

#define NN 100000
#define NE 1600000
#define EPSV 1e-5f
#define NTILE 1563          // ceil(NN/64)

typedef float f32x4 __attribute__((ext_vector_type(4)));
typedef short s16x8 __attribute__((ext_vector_type(8)));

__device__ __forceinline__ unsigned short f2bf(float f) {
  unsigned int u = __float_as_uint(f);
  u += 0x7fffu + ((u >> 16) & 1u);   // round-to-nearest-even
  return (unsigned short)(u >> 16);
}

__device__ __forceinline__ float bf2f(unsigned short s) {
  return __uint_as_float(((unsigned int)s) << 16);
}

__device__ __forceinline__ ushort4 pack4(float4 v) {
  ushort4 s;
  s.x = f2bf(v.x); s.y = f2bf(v.y); s.z = f2bf(v.z); s.w = f2bf(v.w);
  return s;
}

// ---- K1: bucket (4/5 of blocks) ∥ g1a partial GEMM (1/5) ----------------------
__global__ __launch_bounds__(256) void k_bucket_g1a(
    const int* __restrict__ ei, int* __restrict__ cnt, int* __restrict__ eids,
    const float4* __restrict__ x4, const float4* __restrict__ state4,
    const int* __restrict__ batch, const float4* __restrict__ w14,
    f32x4* __restrict__ ph) {
  __shared__ unsigned short lx[64][136];   // x(0..63) + state(64..127) per node
  __shared__ unsigned short lw[64][136];   // W1 x-cols + state-cols per out-row
  const int idx = blockIdx.x;
  const int tid = threadIdx.x;
  const bool is_g1a = ((idx % 5) == 2) && (idx / 5 < NTILE);
  if (!is_g1a) {
    int nga = idx / 5 + (((idx % 5) > 2) ? 1 : 0);   // g1a blocks before idx
    if (nga > NTILE) nga = NTILE;
    int e = (idx - nga) * 256 + tid;                 // bucket_id * 256 + tid
    int src = ei[e];
    int pos = atomicAdd(&cnt[src], 1);
    if (pos < 64) eids[(size_t)src * 64 + pos] = e;
    return;
  }
  const int tile = idx / 5;
  const int nodeBase = tile * 64;
#pragma unroll
  for (int i = 0; i < 4; ++i) {            // W1: x-part q0..15, state-part q32..47
    int t = tid + i * 256;
    int j = t >> 4, q = t & 15;
    *(ushort4*)&lw[j][q * 4]      = pack4(w14[j * 48 + q]);
    *(ushort4*)&lw[j][64 + q * 4] = pack4(w14[j * 48 + 32 + q]);
  }
#pragma unroll
  for (int i = 0; i < 4; ++i) {            // node tile: x + state[batch]
    int t = tid + i * 256;
    int node = t >> 4, q = t & 15;
    int g = nodeBase + node;
    float4 vx = {0,0,0,0}, vs = {0,0,0,0};
    if (g < NN) {
      vx = x4[(size_t)g * 16 + q];
      vs = state4[batch[g] * 16 + q];
    }
    *(ushort4*)&lx[node][q * 4]      = pack4(vx);
    *(ushort4*)&lx[node][64 + q * 4] = pack4(vs);
  }
  __syncthreads();
  const int lane = tid & 63, w = tid >> 6;
  const int rg = lane >> 4, ci = lane & 15;
  f32x4 acc[4] = {{0,0,0,0},{0,0,0,0},{0,0,0,0},{0,0,0,0}};
#pragma unroll
  for (int s = 0; s < 4; ++s) {            // 128 packed k-cols
    int k0 = 32 * s + rg * 8;
    s16x8 a = *(const s16x8*)&lx[w * 16 + ci][k0];
#pragma unroll
    for (int c = 0; c < 4; ++c) {
      s16x8 b = *(const s16x8*)&lw[c * 16 + ci][k0];
      acc[c] = __builtin_amdgcn_mfma_f32_16x16x32_bf16(a, b, acc[c], 0, 0, 0);
    }
  }
#pragma unroll
  for (int c = 0; c < 4; ++c)
    ph[(size_t)tile * 1024 + tid * 4 + c] = acc[c];
}

// ---- K2: fused gather-mean + g1b: one block per 64-node tile -------------------
// Wave w gathers nodes tile*64 + w*16 .. +15 (r6's proven 32-slot clamped body),
// writes vmean bf16 straight to the LDS tile, then the block runs the g1b MFMA
// (ph + vmean @ W1v^T), epilogue, h1 store, and S1/Q1 stats — no vmb round-trip,
// no separate launch, no grid-wide gather/g1b barrier.
__global__ __launch_bounds__(256) void k_gather_g1b(
    const int* __restrict__ cnt, const int* __restrict__ eids,
    const float4* __restrict__ ea4,
    const float4* __restrict__ w14, const float* __restrict__ b1,
    const f32x4* __restrict__ ph, unsigned short* __restrict__ h1,
    float* __restrict__ Sout, float* __restrict__ Qout) {
  __shared__ unsigned short lv[64][72];    // vmean tile
  __shared__ unsigned short lwv[64][72];   // W1 vm-cols; reused as out-tile
  __shared__ float ssum[64], ssq[64];
  const int tid = threadIdx.x;
  const int tile = blockIdx.x;
  const int nodeBase = tile * 64;
  if (tid < 64) { ssum[tid] = 0.f; ssq[tid] = 0.f; }
#pragma unroll
  for (int i = 0; i < 4; ++i) {            // W1 vm-cols (k=64..127)
    int t = tid + i * 256;
    int j = t >> 4, q = t & 15;
    *(ushort4*)&lwv[j][q * 4] = pack4(w14[j * 48 + 16 + q]);
  }
  const int lane = tid & 63, w = tid >> 6;
  const int grp = lane >> 4, q = lane & 15;
  for (int k = 0; k < 16; ++k) {           // 16 nodes per wave
    int n = nodeBase + w * 16 + k;
    float ax = 0.f, ay = 0.f, az = 0.f, aw = 0.f;
    int c = 0;
    if (n < NN) {
      const int* elist = eids + (size_t)n * 64;
      c = cnt[n];
      int m = c < 64 ? c : 64;
      int rm = m - 1;
      {
        int r0 = grp,      r1 = 4 + grp,  r2 = 8 + grp,  r3 = 12 + grp;
        int r4 = 16 + grp, r5 = 20 + grp, r6 = 24 + grp, r7 = 28 + grp;
        int i0 = elist[r0 < m ? r0 : rm];
        int i1 = elist[r1 < m ? r1 : rm];
        int i2 = elist[r2 < m ? r2 : rm];
        int i3 = elist[r3 < m ? r3 : rm];
        int i4 = elist[r4 < m ? r4 : rm];
        int i5 = elist[r5 < m ? r5 : rm];
        int i6 = elist[r6 < m ? r6 : rm];
        int i7 = elist[r7 < m ? r7 : rm];
        float4 v0 = ea4[(size_t)i0 * 16 + q];
        float4 v1 = ea4[(size_t)i1 * 16 + q];
        float4 v2 = ea4[(size_t)i2 * 16 + q];
        float4 v3 = ea4[(size_t)i3 * 16 + q];
        float4 v4 = ea4[(size_t)i4 * 16 + q];
        float4 v5 = ea4[(size_t)i5 * 16 + q];
        float4 v6 = ea4[(size_t)i6 * 16 + q];
        float4 v7 = ea4[(size_t)i7 * 16 + q];
        float m0 = r0 < m ? 1.f : 0.f, m1 = r1 < m ? 1.f : 0.f;
        float m2 = r2 < m ? 1.f : 0.f, m3 = r3 < m ? 1.f : 0.f;
        ax += m0 * v0.x + m1 * v1.x + m2 * v2.x + m3 * v3.x;
        ay += m0 * v0.y + m1 * v1.y + m2 * v2.y + m3 * v3.y;
        az += m0 * v0.z + m1 * v1.z + m2 * v2.z + m3 * v3.z;
        aw += m0 * v0.w + m1 * v1.w + m2 * v2.w + m3 * v3.w;
        float m4 = r4 < m ? 1.f : 0.f, m5 = r5 < m ? 1.f : 0.f;
        float m6 = r6 < m ? 1.f : 0.f, m7 = r7 < m ? 1.f : 0.f;
        ax += m4 * v4.x + m5 * v5.x + m6 * v6.x + m7 * v7.x;
        ay += m4 * v4.y + m5 * v5.y + m6 * v6.y + m7 * v7.y;
        az += m4 * v4.z + m5 * v5.z + m6 * v6.z + m7 * v7.z;
        aw += m4 * v4.w + m5 * v5.w + m6 * v6.w + m7 * v7.w;
      }
      if (m > 32) {                        // rare tail (P ~ 2e-4)
        for (int e = 32; e < m; e += 16) {
          int r0 = e + grp, r1 = e + 4 + grp, r2 = e + 8 + grp, r3 = e + 12 + grp;
          int i0 = elist[r0 < m ? r0 : rm];
          int i1 = elist[r1 < m ? r1 : rm];
          int i2 = elist[r2 < m ? r2 : rm];
          int i3 = elist[r3 < m ? r3 : rm];
          float4 v0 = ea4[(size_t)i0 * 16 + q];
          float4 v1 = ea4[(size_t)i1 * 16 + q];
          float4 v2 = ea4[(size_t)i2 * 16 + q];
          float4 v3 = ea4[(size_t)i3 * 16 + q];
          float m0 = r0 < m ? 1.f : 0.f, m1 = r1 < m ? 1.f : 0.f;
          float m2 = r2 < m ? 1.f : 0.f, m3 = r3 < m ? 1.f : 0.f;
          ax += m0 * v0.x + m1 * v1.x + m2 * v2.x + m3 * v3.x;
          ay += m0 * v0.y + m1 * v1.y + m2 * v2.y + m3 * v3.y;
          az += m0 * v0.z + m1 * v1.z + m2 * v2.z + m3 * v3.z;
          aw += m0 * v0.w + m1 * v1.w + m2 * v2.w + m3 * v3.w;
        }
      }
    }
    ax += __shfl_xor(ax, 16); ay += __shfl_xor(ay, 16);
    az += __shfl_xor(az, 16); aw += __shfl_xor(aw, 16);
    ax += __shfl_xor(ax, 32); ay += __shfl_xor(ay, 32);
    az += __shfl_xor(az, 32); aw += __shfl_xor(aw, 32);
    if (lane < 16) {
      float inv = 1.0f / fmaxf((float)c, 1.0f);
      float4 r; r.x = ax * inv; r.y = ay * inv; r.z = az * inv; r.w = aw * inv;
      *(ushort4*)&lv[w * 16 + k][lane * 4] = pack4(r);
    }
  }
  __syncthreads();
  const int rg = lane >> 4, ci = lane & 15;
  f32x4 acc[4];
#pragma unroll
  for (int cc = 0; cc < 4; ++cc) acc[cc] = ph[(size_t)tile * 1024 + tid * 4 + cc];
#pragma unroll
  for (int s = 0; s < 2; ++s) {
    int k0 = 32 * s + rg * 8;
    s16x8 a = *(const s16x8*)&lv[w * 16 + ci][k0];
#pragma unroll
    for (int cc = 0; cc < 4; ++cc) {
      s16x8 b = *(const s16x8*)&lwv[cc * 16 + ci][k0];
      acc[cc] = __builtin_amdgcn_mfma_f32_16x16x32_bf16(a, b, acc[cc], 0, 0, 0);
    }
  }
  __syncthreads();                         // lwv reads done; reuse as out-tile
  unsigned short (*lo)[72] = (unsigned short(*)[72])lwv;
#pragma unroll
  for (int cc = 0; cc < 4; ++cc) {
    int col = cc * 16 + ci;
    float bb = b1[col];
    float ls = 0.f, lq = 0.f;
#pragma unroll
    for (int r = 0; r < 4; ++r) {
      int row = w * 16 + rg * 4 + r;
      float v = fmaxf(acc[cc][r] + bb, 0.f);
      lo[row][col] = f2bf(v);
      if (nodeBase + row < NN) { ls += v; lq += v * v; }
    }
    atomicAdd(&ssum[col], ls);
    atomicAdd(&ssq[col], lq);
  }
  __syncthreads();
#pragma unroll
  for (int i = 0; i < 2; ++i) {            // coalesced 16B stores
    int t = tid + i * 256;
    int row = t >> 3, q2 = t & 7;
    int g = nodeBase + row;
    if (g < NN) *(s16x8*)&h1[(size_t)g * 64 + q2 * 8] = *(const s16x8*)&lo[row][q2 * 8];
  }
  if (tid < 64) {
    unsafeAtomicAdd(&Sout[tid], ssum[tid]);
    unsafeAtomicAdd(&Qout[tid], ssq[tid]);
  }
}

// ---- GEMM2/3 with in-kernel BN fold: out = [relu](A @ Wf^T + d) ---------------
template <bool RELU>
__global__ __launch_bounds__(256) void k_gemm64f(
    const s16x8* __restrict__ A8,     // bf16 [NN][64]
    const float* __restrict__ Wf,     // f32 [64][64] raw weights
    const float* __restrict__ bias,
    const float* __restrict__ gm, const float* __restrict__ bt,
    const float* __restrict__ Sin, const float* __restrict__ Qin,
    unsigned short* __restrict__ Obf,
    float* __restrict__ Sout, float* __restrict__ Qout) {
  __shared__ unsigned short la[64][72];    // A tile; reused as out-tile
  __shared__ unsigned short lwf[64][72];   // folded W bf16
  __shared__ float lA[64], lC[64], ld[64], red[256], ssum[64], ssq[64];
  const int tid = threadIdx.x;
  const int nodeBase = blockIdx.x * 64;
  if (tid < 64) {
    float mu = Sin[tid] * (1.0f / NN);
    float var = Qin[tid] * (1.0f / NN) - mu * mu;
    float a = gm[tid] * rsqrtf(var + EPSV);
    lA[tid] = a; lC[tid] = bt[tid] - mu * a;
    ssum[tid] = 0.f; ssq[tid] = 0.f;
  }
  __syncthreads();
#pragma unroll
  for (int i = 0; i < 2; ++i) {            // A tile: 512 x 16B
    int t = tid + i * 256;
    int row = t >> 3, q = t & 7;
    int g = nodeBase + row;
    s16x8 v = {};
    if (g < NN) v = A8[(size_t)g * 8 + q];
    *(s16x8*)&la[row][q * 8] = v;
  }
#pragma unroll
  for (int i = 0; i < 16; ++i) {           // fold weights by BN scale a_k
    int t = tid + i * 256;
    lwf[t >> 6][t & 63] = f2bf(Wf[t] * lA[t & 63]);
  }
  {                                        // folded bias partials
    int j = tid >> 2, p = tid & 3;
    const float* Wr = Wf + j * 64 + p * 16;
    float s = 0.f;
#pragma unroll
    for (int k = 0; k < 16; ++k) s += lC[p * 16 + k] * Wr[k];
    red[tid] = s;
  }
  __syncthreads();
  if (tid < 64) ld[tid] = bias[tid] + red[tid*4] + red[tid*4+1] + red[tid*4+2] + red[tid*4+3];
  __syncthreads();
  const int lane = tid & 63, w = tid >> 6;
  const int rg = lane >> 4, ci = lane & 15;
  f32x4 acc[4] = {{0,0,0,0},{0,0,0,0},{0,0,0,0},{0,0,0,0}};
#pragma unroll
  for (int s = 0; s < 2; ++s) {
    int k0 = 32 * s + rg * 8;
    s16x8 a = *(const s16x8*)&la[w * 16 + ci][k0];
#pragma unroll
    for (int c = 0; c < 4; ++c) {
      s16x8 b = *(const s16x8*)&lwf[c * 16 + ci][k0];
      acc[c] = __builtin_amdgcn_mfma_f32_16x16x32_bf16(a, b, acc[c], 0, 0, 0);
    }
  }
  __syncthreads();                         // reuse la as out-tile
  unsigned short (*lo)[72] = (unsigned short(*)[72])la;
#pragma unroll
  for (int c = 0; c < 4; ++c) {
    int col = c * 16 + ci;
    float dd = ld[col];
    float ls = 0.f, lq = 0.f;
#pragma unroll
    for (int r = 0; r < 4; ++r) {
      int row = w * 16 + rg * 4 + r;
      float v = acc[c][r] + dd;
      if (RELU) v = fmaxf(v, 0.f);
      lo[row][col] = f2bf(v);
      if (nodeBase + row < NN) { ls += v; lq += v * v; }
    }
    atomicAdd(&ssum[col], ls);
    atomicAdd(&ssq[col], lq);
  }
  __syncthreads();
#pragma unroll
  for (int i = 0; i < 2; ++i) {
    int t = tid + i * 256;
    int row = t >> 3, q = t & 7;
    int g = nodeBase + row;
    if (g < NN) *(s16x8*)&Obf[(size_t)g * 64 + q * 8] = *(const s16x8*)&lo[row][q * 8];
  }
  if (tid < 64) {
    unsafeAtomicAdd(&Sout[tid], ssum[tid]);
    unsafeAtomicAdd(&Qout[tid], ssq[tid]);
  }
}

// ---- final BN3 elementwise (bf16 in, f32 out) ---------------------------------
__global__ __launch_bounds__(256) void k_bn3(
    const s16x8* __restrict__ h3b, const float* __restrict__ gm,
    const float* __restrict__ bt, const float* __restrict__ S,
    const float* __restrict__ Q, float4* __restrict__ out) {
  __shared__ float lA[64], lC[64];
  const int tid = threadIdx.x;
  if (tid < 64) {
    float mu = S[tid] * (1.0f / NN);
    float var = Q[tid] * (1.0f / NN) - mu * mu;
    float a = gm[tid] * rsqrtf(var + EPSV);
    lA[tid] = a;
    lC[tid] = bt[tid] - mu * a;
  }
  __syncthreads();
  const int total = NN * 8;                // short8 units
  for (int idx = blockIdx.x * 256 + tid; idx < total; idx += gridDim.x * 256) {
    s16x8 v = h3b[idx];
    int k = (idx & 7) * 8;
    float4 o0, o1;
    o0.x = bf2f((unsigned short)v[0]) * lA[k]     + lC[k];
    o0.y = bf2f((unsigned short)v[1]) * lA[k + 1] + lC[k + 1];
    o0.z = bf2f((unsigned short)v[2]) * lA[k + 2] + lC[k + 2];
    o0.w = bf2f((unsigned short)v[3]) * lA[k + 3] + lC[k + 3];
    o1.x = bf2f((unsigned short)v[4]) * lA[k + 4] + lC[k + 4];
    o1.y = bf2f((unsigned short)v[5]) * lA[k + 5] + lC[k + 5];
    o1.z = bf2f((unsigned short)v[6]) * lA[k + 6] + lC[k + 6];
    o1.w = bf2f((unsigned short)v[7]) * lA[k + 7] + lC[k + 7];
    out[idx * 2]     = o0;
    out[idx * 2 + 1] = o1;
  }
}

extern "C" void kernel_launch(void* const* d_in, const int* in_sizes, int n_in,
                              void* d_out, int out_size, void* d_ws, size_t ws_size,
                              hipStream_t stream) {
  const float* x     = (const float*)d_in[0];
  const int*   ei    = (const int*)d_in[1];
  const float* ea    = (const float*)d_in[2];
  const float* state = (const float*)d_in[3];
  const int*   batch = (const int*)d_in[4];
  const float* W1  = (const float*)d_in[5];
  const float* b1  = (const float*)d_in[6];
  const float* g1  = (const float*)d_in[7];
  const float* be1 = (const float*)d_in[8];
  const float* W2  = (const float*)d_in[9];
  const float* b2  = (const float*)d_in[10];
  const float* g2  = (const float*)d_in[11];
  const float* be2 = (const float*)d_in[12];
  const float* W3  = (const float*)d_in[13];
  const float* b3  = (const float*)d_in[14];
  const float* g3  = (const float*)d_in[15];
  const float* be3 = (const float*)d_in[16];

  // Workspace layout:
  //   [0,        400000)   cnt
  //   [400000,   401536)   stats S1 Q1 S2 Q2 S3 Q3
  //   [401536,  26018432)  eids (int, 64/node)   == h3 bf16 alias (12.8 MB)
  //   [26018432,38818432)  h2 bf16
  //   [38818432,51618432)  h1 bf16
  //   [51618432,77218432)  ph f32 partial (g1a -> gather_g1b)
  char* ws = (char*)d_ws;
  int*   cnt  = (int*)ws;
  float* S1   = (float*)(ws + 400000);
  float* Q1 = S1 + 64;
  float* S2 = S1 + 128;
  float* Q2 = S1 + 192;
  float* S3 = S1 + 256;
  float* Q3 = S1 + 320;
  int*            eids = (int*)(ws + 401536);
  unsigned short* h3b  = (unsigned short*)(ws + 401536);   // alias eids
  unsigned short* h2   = (unsigned short*)(ws + 26018432);
  unsigned short* h1   = (unsigned short*)(ws + 38818432);
  f32x4*          ph   = (f32x4*)(ws + 51618432);

  hipMemsetAsync(ws, 0, 401536, stream);   // cnt + stats

  k_bucket_g1a<<<6250 + NTILE, 256, 0, stream>>>(
      ei, cnt, eids, (const float4*)x, (const float4*)state, batch,
      (const float4*)W1, ph);
  k_gather_g1b<<<NTILE, 256, 0, stream>>>(cnt, eids, (const float4*)ea,
                                          (const float4*)W1, b1, ph, h1, S1, Q1);
  k_gemm64f<true><<<NTILE, 256, 0, stream>>>(
      (const s16x8*)h1, W2, b2, g1, be1, S1, Q1, h2, S2, Q2);
  k_gemm64f<false><<<NTILE, 256, 0, stream>>>(
      (const s16x8*)h2, W3, b3, g2, be2, S2, Q2, h3b, S3, Q3);
  k_bn3<<<2048, 256, 0, stream>>>((const s16x8*)h3b, g3, be3, S3, Q3, (float4*)d_out);
}